// Round 3
// baseline (804.610 us; speedup 1.0000x reference)
//
#include <hip/hip_runtime.h>
#include <math.h>

#define NNODES 50000
#define NEDGES 800000

// ============ zero-LDS SGPR-broadcast GEMM ============
// Each wave computes C[m0..m0+31][col-slab of 64]. B chunk (32xK) held in
// VGPRs (per-lane column), A elements are wave-uniform -> scalar loads.
// K must be a multiple of 32. Grid: (Nc/64, ceil(M/128)), 256 threads.
__global__ __launch_bounds__(256) void gemm_sb(const float* __restrict__ A,
                                               const float* __restrict__ B,
                                               float* __restrict__ C, int M, int K, int Nc) {
    int wave = threadIdx.x >> 6, lane = threadIdx.x & 63;
    int m0 = (blockIdx.y * 4 + wave) * 32;
    int col = blockIdx.x * 64 + lane;
    if (m0 >= M) return;
    float acc[32];
#pragma unroll
    for (int m = 0; m < 32; m++) acc[m] = 0.f;
    for (int k0 = 0; k0 < K; k0 += 32) {
        float breg[32];
#pragma unroll
        for (int j = 0; j < 32; j++) breg[j] = B[(size_t)(k0 + j) * Nc + col];
#pragma unroll
        for (int m = 0; m < 32; m++) {
            int mr = m0 + m;
            if (mr > M - 1) mr = M - 1;  // clamp: reads valid rows, result discarded
            const float* arow = A + (size_t)mr * K + k0;
#pragma unroll
            for (int j = 0; j < 32; j++) acc[m] = fmaf(arow[j], breg[j], acc[m]);
        }
    }
#pragma unroll
    for (int m = 0; m < 32; m++) {
        int mr = m0 + m;
        if (mr < M) C[(size_t)mr * Nc + col] = acc[m];
    }
}

// ============ per-node attention scalars ============
template <int H>
__global__ void asad_kernel(const float* __restrict__ hbuf, const float* __restrict__ a_src,
                            const float* __restrict__ a_dst, float* __restrict__ as_,
                            float* __restrict__ ad_, int n) {
    int node = blockIdx.x * 4 + (threadIdx.x >> 6);
    int lane = threadIdx.x & 63;
    if (node >= n) return;
#pragma unroll
    for (int hh = 0; hh < H; hh++) {
        float v = hbuf[(size_t)node * (H * 64) + hh * 64 + lane];
        float vs = v * a_src[hh * 64 + lane];
        float vd = v * a_dst[hh * 64 + lane];
#pragma unroll
        for (int off = 32; off > 0; off >>= 1) {
            vs += __shfl_down(vs, off);
            vd += __shfl_down(vd, off);
        }
        if (lane == 0) {
            as_[node * H + hh] = vs;
            ad_[node * H + hh] = vd;
        }
    }
}

// ============ CSR build ============
__global__ void deg_hist(const int* __restrict__ ei, int* __restrict__ deg, int nE, int nT) {
    int idx = blockIdx.x * blockDim.x + threadIdx.x;
    if (idx >= nT) return;
    int dst = (idx < nE) ? ei[nE + idx] : idx - nE;
    atomicAdd(&deg[dst], 1);
}

__global__ void scan_block(const int* __restrict__ deg, int* __restrict__ rowptr,
                           int* __restrict__ blocksums, int n) {
    __shared__ int tmp[256];
    int tid = threadIdx.x;
    int gid = blockIdx.x * 256 + tid;
    int v = (gid < n) ? deg[gid] : 0;
    tmp[tid] = v;
    __syncthreads();
    for (int off = 1; off < 256; off <<= 1) {
        int t = (tid >= off) ? tmp[tid - off] : 0;
        __syncthreads();
        tmp[tid] += t;
        __syncthreads();
    }
    if (gid < n) rowptr[gid] = tmp[tid] - v;
    if (tid == 255) blocksums[blockIdx.x] = tmp[tid];
}

__global__ void scan_sums(int* __restrict__ bs, int nb) {
    __shared__ int tmp[256];
    int tid = threadIdx.x;
    int v = (tid < nb) ? bs[tid] : 0;
    tmp[tid] = v;
    __syncthreads();
    for (int off = 1; off < 256; off <<= 1) {
        int t = (tid >= off) ? tmp[tid - off] : 0;
        __syncthreads();
        tmp[tid] += t;
        __syncthreads();
    }
    if (tid < nb) bs[tid] = tmp[tid] - v;
}

__global__ void scan_add(int* __restrict__ rowptr, const int* __restrict__ bs,
                         int* __restrict__ cursor, int n, int nT) {
    int gid = blockIdx.x * 256 + threadIdx.x;
    if (gid < n) {
        int r = rowptr[gid] + bs[blockIdx.x];
        rowptr[gid] = r;
        cursor[gid] = r;
    }
    if (gid == 0) rowptr[n] = nT;
}

__global__ void csr_scatter(const int* __restrict__ ei, int* __restrict__ cursor,
                            int* __restrict__ csr_src, int nE, int nT) {
    int idx = blockIdx.x * blockDim.x + threadIdx.x;
    if (idx >= nT) return;
    int src, dst;
    if (idx < nE) { src = ei[idx]; dst = ei[nE + idx]; } else { src = dst = idx - nE; }
    int pos = atomicAdd(&cursor[dst], 1);
    csr_src[pos] = src;
}

// ============ fused per-node softmax+agg+bias+ELU, H=4 C=64 ============
// one wave per node; lane owns channels 4*lane..4*lane+3 (head = lane>>4)
__global__ void node_agg4(const int* __restrict__ rowptr, const int* __restrict__ csr,
                          const float* __restrict__ as_, const float* __restrict__ ad_,
                          const float* __restrict__ hbuf, const float* __restrict__ b,
                          float* __restrict__ out, int n) {
    int node = blockIdx.x * 4 + (threadIdx.x >> 6);
    int lane = threadIdx.x & 63;
    if (node >= n) return;
    int beg = rowptr[node], end = rowptr[node + 1];
    int head = lane >> 4;

    float4 adv = *(const float4*)&ad_[node * 4];
    float adn[4] = {adv.x, adv.y, adv.z, adv.w};
    float mh[4], sh[4];
#pragma unroll
    for (int h = 0; h < 4; h++) { mh[h] = -1e30f; sh[h] = 0.f; }

    // pass A: online softmax stats, lanes stride over edges
    for (int i = beg + lane; i < end; i += 64) {
        int src = csr[i];
        float4 asv = *(const float4*)&as_[src * 4];
        float e[4] = {asv.x + adn[0], asv.y + adn[1], asv.z + adn[2], asv.w + adn[3]};
#pragma unroll
        for (int h = 0; h < 4; h++) {
            float ev = e[h] > 0.f ? e[h] : 0.2f * e[h];
            if (ev > mh[h]) {
                sh[h] = sh[h] * __expf(mh[h] - ev) + 1.f;
                mh[h] = ev;
            } else {
                sh[h] += __expf(ev - mh[h]);
            }
        }
    }
#pragma unroll
    for (int off = 32; off > 0; off >>= 1) {
#pragma unroll
        for (int h = 0; h < 4; h++) {
            float m2 = __shfl_down(mh[h], off);
            float s2 = __shfl_down(sh[h], off);
            float mn = fmaxf(mh[h], m2);
            sh[h] = sh[h] * __expf(mh[h] - mn) + s2 * __expf(m2 - mn);
            mh[h] = mn;
        }
    }
    float inv_s[4];
#pragma unroll
    for (int h = 0; h < 4; h++) {
        mh[h] = __shfl(mh[h], 0);
        sh[h] = __shfl(sh[h], 0);
        inv_s[h] = 1.f / (sh[h] + 1e-16f);
    }

    // pass B: lane j precomputes alpha for edge base+j; broadcast via shfl
    float4 acc = make_float4(0.f, 0.f, 0.f, 0.f);
    for (int base = beg; base < end; base += 64) {
        int cnt = end - base;
        if (cnt > 64) cnt = 64;
        int my_src = csr[base + (lane < cnt ? lane : 0)];
        float4 asv = *(const float4*)&as_[my_src * 4];
        float e[4] = {asv.x + adn[0], asv.y + adn[1], asv.z + adn[2], asv.w + adn[3]};
        float myal[4];
#pragma unroll
        for (int h = 0; h < 4; h++) {
            float ev = e[h] > 0.f ? e[h] : 0.2f * e[h];
            myal[h] = __expf(ev - mh[h]) * inv_s[h];
        }
        for (int j = 0; j < cnt; j++) {
            int src = __shfl(my_src, j);
            float a0 = __shfl(myal[0], j);
            float a1 = __shfl(myal[1], j);
            float a2 = __shfl(myal[2], j);
            float a3 = __shfl(myal[3], j);
            float al = head < 2 ? (head == 0 ? a0 : a1) : (head == 2 ? a2 : a3);
            float4 v = *(const float4*)&hbuf[(size_t)src * 256 + lane * 4];
            acc.x = fmaf(al, v.x, acc.x);
            acc.y = fmaf(al, v.y, acc.y);
            acc.z = fmaf(al, v.z, acc.z);
            acc.w = fmaf(al, v.w, acc.w);
        }
    }
    float4 bv = *(const float4*)&b[lane * 4];
    acc.x += bv.x; acc.y += bv.y; acc.z += bv.z; acc.w += bv.w;
    acc.x = acc.x > 0.f ? acc.x : __expf(acc.x) - 1.f;
    acc.y = acc.y > 0.f ? acc.y : __expf(acc.y) - 1.f;
    acc.z = acc.z > 0.f ? acc.z : __expf(acc.z) - 1.f;
    acc.w = acc.w > 0.f ? acc.w : __expf(acc.w) - 1.f;
    *(float4*)&out[(size_t)node * 256 + lane * 4] = acc;
}

// ============ fused per-node softmax+agg+bias+ELU, H=1 C=64 ============
__global__ void node_agg1(const int* __restrict__ rowptr, const int* __restrict__ csr,
                          const float* __restrict__ as_, const float* __restrict__ ad_,
                          const float* __restrict__ hbuf, const float* __restrict__ b,
                          float* __restrict__ out, int n) {
    int node = blockIdx.x * 4 + (threadIdx.x >> 6);
    int lane = threadIdx.x & 63;
    if (node >= n) return;
    int beg = rowptr[node], end = rowptr[node + 1];

    float adn = ad_[node];
    float mh = -1e30f, sh = 0.f;
    for (int i = beg + lane; i < end; i += 64) {
        int src = csr[i];
        float ev = as_[src] + adn;
        ev = ev > 0.f ? ev : 0.2f * ev;
        if (ev > mh) {
            sh = sh * __expf(mh - ev) + 1.f;
            mh = ev;
        } else {
            sh += __expf(ev - mh);
        }
    }
#pragma unroll
    for (int off = 32; off > 0; off >>= 1) {
        float m2 = __shfl_down(mh, off);
        float s2 = __shfl_down(sh, off);
        float mn = fmaxf(mh, m2);
        sh = sh * __expf(mh - mn) + s2 * __expf(m2 - mn);
        mh = mn;
    }
    mh = __shfl(mh, 0);
    sh = __shfl(sh, 0);
    float inv_s = 1.f / (sh + 1e-16f);

    float acc = 0.f;
    for (int base = beg; base < end; base += 64) {
        int cnt = end - base;
        if (cnt > 64) cnt = 64;
        int my_src = csr[base + (lane < cnt ? lane : 0)];
        float ev = as_[my_src] + adn;
        ev = ev > 0.f ? ev : 0.2f * ev;
        float myal = __expf(ev - mh) * inv_s;
        for (int j = 0; j < cnt; j++) {
            int src = __shfl(my_src, j);
            float al = __shfl(myal, j);
            acc = fmaf(al, hbuf[(size_t)src * 64 + lane], acc);
        }
    }
    float v = acc + b[lane];
    out[(size_t)node * 64 + lane] = v > 0.f ? v : __expf(v) - 1.f;
}

// ============ fused classifier ============
__global__ void classifier_kernel(const float* __restrict__ z, const float* __restrict__ W3,
                                  const float* __restrict__ b3, const float* __restrict__ W4,
                                  const float* __restrict__ b4, float* __restrict__ out, int n) {
    __shared__ float zt[64][65];
    __shared__ float w3s[64 * 32];
    __shared__ float hid[64][33];
    __shared__ float w4s[64], b3s[32], b4s[2];
    int t = threadIdx.x;
    int r0 = blockIdx.x * 64;
#pragma unroll
    for (int i = 0; i < 16; i++) {
        int j = i * 256 + t;
        int row = j >> 6, col = j & 63;
        int gr = r0 + row;
        zt[row][col] = (gr < n) ? z[(size_t)gr * 64 + col] : 0.f;
    }
#pragma unroll
    for (int i = 0; i < 8; i++) w3s[i * 256 + t] = W3[i * 256 + t];
    if (t < 64) w4s[t] = W4[t];
    if (t < 32) b3s[t] = b3[t];
    if (t < 2) b4s[t] = b4[t];
    __syncthreads();
#pragma unroll
    for (int i = 0; i < 8; i++) {
        int row = (t >> 5) + i * 8;
        int col = t & 31;
        float acc = b3s[col];
#pragma unroll
        for (int k = 0; k < 64; k++) acc += zt[row][k] * w3s[k * 32 + col];
        hid[row][col] = acc > 0.f ? acc : 0.f;
    }
    __syncthreads();
    if (t < 128) {
        int row = t >> 1, c = t & 1;
        int gr = r0 + row;
        if (gr < n) {
            float acc = b4s[c];
#pragma unroll
            for (int k = 0; k < 32; k++) acc += hid[row][k] * w4s[k * 2 + c];
            out[(size_t)gr * 2 + c] = acc;
        }
    }
}

extern "C" void kernel_launch(void* const* d_in, const int* in_sizes, int n_in,
                              void* d_out, int out_size, void* d_ws, size_t ws_size,
                              hipStream_t stream) {
    const float* x      = (const float*)d_in[0];
    const int*   ei     = (const int*)d_in[1];
    const float* W1     = (const float*)d_in[2];
    const float* a_src1 = (const float*)d_in[3];
    const float* a_dst1 = (const float*)d_in[4];
    const float* b1     = (const float*)d_in[5];
    const float* W2     = (const float*)d_in[6];
    const float* a_src2 = (const float*)d_in[7];
    const float* a_dst2 = (const float*)d_in[8];
    const float* b2     = (const float*)d_in[9];
    const float* W3     = (const float*)d_in[10];
    const float* b3     = (const float*)d_in[11];
    const float* W4     = (const float*)d_in[12];
    const float* b4     = (const float*)d_in[13];
    float* out = (float*)d_out;

    const int N = NNODES, E = NEDGES, ET = E + N;
    const int NB = (N + 255) / 256;

    float* ws = (float*)d_ws;
    size_t o = 0;
    float* h1   = ws + o; o += (size_t)N * 256;
    float* out1 = ws + o; o += (size_t)N * 256;
    float* as1  = ws + o; o += (size_t)N * 4;
    float* ad1  = ws + o; o += (size_t)N * 4;
    int* ibase     = (int*)(ws + o);
    int* rowptr    = ibase;
    int* cursor    = rowptr + (N + 1);
    int* blocksums = cursor + N;
    int* csr_src   = blocksums + 256;
    float* h2   = h1;
    float* out2 = h1 + (size_t)N * 64;

    dim3 blk(256);

    // ---- CSR build (shared by both layers) ----
    hipMemsetAsync(cursor, 0, (size_t)N * sizeof(int), stream);
    deg_hist<<<(ET + 255) / 256, blk, 0, stream>>>(ei, cursor, E, ET);
    scan_block<<<NB, blk, 0, stream>>>(cursor, rowptr, blocksums, N);
    scan_sums<<<1, blk, 0, stream>>>(blocksums, NB);
    scan_add<<<NB, blk, 0, stream>>>(rowptr, blocksums, cursor, N, ET);
    csr_scatter<<<(ET + 255) / 256, blk, 0, stream>>>(ei, cursor, csr_src, E, ET);

    // ---- Layer 1 (H=4, C=64) ----
    gemm_sb<<<dim3(4, (N + 127) / 128), blk, 0, stream>>>(x, W1, h1, N, 128, 256);
    asad_kernel<4><<<(N + 3) / 4, blk, 0, stream>>>(h1, a_src1, a_dst1, as1, ad1, N);
    node_agg4<<<(N + 3) / 4, blk, 0, stream>>>(rowptr, csr_src, as1, ad1, h1, b1, out1, N);

    // ---- Layer 2 (H=1, C=64) ----
    gemm_sb<<<dim3(1, (N + 127) / 128), blk, 0, stream>>>(out1, W2, h2, N, 256, 64);
    asad_kernel<1><<<(N + 3) / 4, blk, 0, stream>>>(h2, a_src2, a_dst2, as1, ad1, N);
    node_agg1<<<(N + 3) / 4, blk, 0, stream>>>(rowptr, csr_src, as1, ad1, h2, b2, out2, N);

    // ---- Classifier ----
    classifier_kernel<<<(N + 63) / 64, blk, 0, stream>>>(out2, W3, b3, W4, b4, out, N);
}

// Round 4
// 517.775 us; speedup vs baseline: 1.5540x; 1.5540x over previous
//
#include <hip/hip_runtime.h>
#include <math.h>

#define NNODES 50000
#define NEDGES 800000

// ============ canonical fp32 tiled GEMM ============
// BM=64, BK=16, TM=4; 256 threads as 16(tx: N) x 16(ty: M).
// BN=128/TN=8 or BN=64/TN=4. Coalesced float4 staging, ds_read_b128 fragments.
template <int BN, int TN>
__global__ __launch_bounds__(256) void gemm_tile(const float* __restrict__ A,
                                                 const float* __restrict__ B,
                                                 float* __restrict__ C, int M, int K, int Nc) {
    __shared__ float As[16][68];   // transposed: As[k][m], pad 68 keeps 16B align, 2-way banks
    __shared__ float Bs[16][BN];
    int tid = threadIdx.x;
    int m0 = blockIdx.y * 64, n0 = blockIdx.x * BN;
    int tx = tid & 15, ty = tid >> 4;
    float acc[4][TN];
#pragma unroll
    for (int i = 0; i < 4; i++)
#pragma unroll
        for (int j = 0; j < TN; j++) acc[i][j] = 0.f;

    for (int k0 = 0; k0 < K; k0 += 16) {
        // stage A: 64x16, one float4 per thread along K, store transposed
        {
            int r = tid >> 2, c = (tid & 3) * 4;
            int gr = m0 + r;
            if (gr > M - 1) gr = M - 1;  // clamp (results for padded rows discarded)
            float4 v = *(const float4*)&A[(size_t)gr * K + k0 + c];
            As[c][r] = v.x; As[c + 1][r] = v.y; As[c + 2][r] = v.z; As[c + 3][r] = v.w;
        }
        // stage B: 16xBN, BN/64 float4 per thread, coalesced
#pragma unroll
        for (int f = 0; f < BN / 64; f++) {
            int idx = f * 256 + tid;
            int r = idx / (BN / 4), c = (idx % (BN / 4)) * 4;
            *(float4*)&Bs[r][c] = *(const float4*)&B[(size_t)(k0 + r) * Nc + n0 + c];
        }
        __syncthreads();
#pragma unroll
        for (int kk = 0; kk < 16; kk++) {
            float4 av = *(const float4*)&As[kk][ty * 4];
            float a[4] = {av.x, av.y, av.z, av.w};
            float b[TN];
#pragma unroll
            for (int j4 = 0; j4 < TN / 4; j4++) {
                float4 bv = *(const float4*)&Bs[kk][tx * TN + j4 * 4];
                b[j4 * 4] = bv.x; b[j4 * 4 + 1] = bv.y;
                b[j4 * 4 + 2] = bv.z; b[j4 * 4 + 3] = bv.w;
            }
#pragma unroll
            for (int i = 0; i < 4; i++)
#pragma unroll
                for (int j = 0; j < TN; j++) acc[i][j] = fmaf(a[i], b[j], acc[i][j]);
        }
        __syncthreads();
    }
#pragma unroll
    for (int i = 0; i < 4; i++) {
        int gr = m0 + ty * 4 + i;
        if (gr >= M) continue;
#pragma unroll
        for (int j4 = 0; j4 < TN / 4; j4++) {
            float4 v = make_float4(acc[i][j4 * 4], acc[i][j4 * 4 + 1],
                                   acc[i][j4 * 4 + 2], acc[i][j4 * 4 + 3]);
            *(float4*)&C[(size_t)gr * Nc + n0 + tx * TN + j4 * 4] = v;
        }
    }
}

// ============ per-node attention scalars ============
template <int H>
__global__ void asad_kernel(const float* __restrict__ hbuf, const float* __restrict__ a_src,
                            const float* __restrict__ a_dst, float* __restrict__ as_,
                            float* __restrict__ ad_, int n) {
    int node = blockIdx.x * 4 + (threadIdx.x >> 6);
    int lane = threadIdx.x & 63;
    if (node >= n) return;
#pragma unroll
    for (int hh = 0; hh < H; hh++) {
        float v = hbuf[(size_t)node * (H * 64) + hh * 64 + lane];
        float vs = v * a_src[hh * 64 + lane];
        float vd = v * a_dst[hh * 64 + lane];
#pragma unroll
        for (int off = 32; off > 0; off >>= 1) {
            vs += __shfl_down(vs, off);
            vd += __shfl_down(vd, off);
        }
        if (lane == 0) {
            as_[node * H + hh] = vs;
            ad_[node * H + hh] = vd;
        }
    }
}

// ============ CSR build ============
__global__ void deg_hist(const int* __restrict__ ei, int* __restrict__ deg, int nE, int nT) {
    int idx = blockIdx.x * blockDim.x + threadIdx.x;
    if (idx >= nT) return;
    int dst = (idx < nE) ? ei[nE + idx] : idx - nE;
    atomicAdd(&deg[dst], 1);
}

__global__ void scan_block(const int* __restrict__ deg, int* __restrict__ rowptr,
                           int* __restrict__ blocksums, int n) {
    __shared__ int tmp[256];
    int tid = threadIdx.x;
    int gid = blockIdx.x * 256 + tid;
    int v = (gid < n) ? deg[gid] : 0;
    tmp[tid] = v;
    __syncthreads();
    for (int off = 1; off < 256; off <<= 1) {
        int t = (tid >= off) ? tmp[tid - off] : 0;
        __syncthreads();
        tmp[tid] += t;
        __syncthreads();
    }
    if (gid < n) rowptr[gid] = tmp[tid] - v;
    if (tid == 255) blocksums[blockIdx.x] = tmp[tid];
}

__global__ void scan_sums(int* __restrict__ bs, int nb) {
    __shared__ int tmp[256];
    int tid = threadIdx.x;
    int v = (tid < nb) ? bs[tid] : 0;
    tmp[tid] = v;
    __syncthreads();
    for (int off = 1; off < 256; off <<= 1) {
        int t = (tid >= off) ? tmp[tid - off] : 0;
        __syncthreads();
        tmp[tid] += t;
        __syncthreads();
    }
    if (tid < nb) bs[tid] = tmp[tid] - v;
}

__global__ void scan_add(int* __restrict__ rowptr, const int* __restrict__ bs,
                         int* __restrict__ cursor, int n, int nT) {
    int gid = blockIdx.x * 256 + threadIdx.x;
    if (gid < n) {
        int r = rowptr[gid] + bs[blockIdx.x];
        rowptr[gid] = r;
        cursor[gid] = r;
    }
    if (gid == 0) rowptr[n] = nT;
}

__global__ void csr_scatter(const int* __restrict__ ei, int* __restrict__ cursor,
                            int* __restrict__ csr_src, int nE, int nT) {
    int idx = blockIdx.x * blockDim.x + threadIdx.x;
    if (idx >= nT) return;
    int src, dst;
    if (idx < nE) { src = ei[idx]; dst = ei[nE + idx]; } else { src = dst = idx - nE; }
    int pos = atomicAdd(&cursor[dst], 1);
    csr_src[pos] = src;
}

// ============ fused per-node softmax+agg+bias+ELU, H=4 C=64 ============
__global__ void node_agg4(const int* __restrict__ rowptr, const int* __restrict__ csr,
                          const float* __restrict__ as_, const float* __restrict__ ad_,
                          const float* __restrict__ hbuf, const float* __restrict__ b,
                          float* __restrict__ out, int n) {
    int node = blockIdx.x * 4 + (threadIdx.x >> 6);
    int lane = threadIdx.x & 63;
    if (node >= n) return;
    int beg = rowptr[node], end = rowptr[node + 1];
    int head = lane >> 4;

    float4 adv = *(const float4*)&ad_[node * 4];
    float adn[4] = {adv.x, adv.y, adv.z, adv.w};
    float mh[4], sh[4];
#pragma unroll
    for (int h = 0; h < 4; h++) { mh[h] = -1e30f; sh[h] = 0.f; }

    for (int i = beg + lane; i < end; i += 64) {
        int src = csr[i];
        float4 asv = *(const float4*)&as_[src * 4];
        float e[4] = {asv.x + adn[0], asv.y + adn[1], asv.z + adn[2], asv.w + adn[3]};
#pragma unroll
        for (int h = 0; h < 4; h++) {
            float ev = e[h] > 0.f ? e[h] : 0.2f * e[h];
            if (ev > mh[h]) {
                sh[h] = sh[h] * __expf(mh[h] - ev) + 1.f;
                mh[h] = ev;
            } else {
                sh[h] += __expf(ev - mh[h]);
            }
        }
    }
#pragma unroll
    for (int off = 32; off > 0; off >>= 1) {
#pragma unroll
        for (int h = 0; h < 4; h++) {
            float m2 = __shfl_down(mh[h], off);
            float s2 = __shfl_down(sh[h], off);
            float mn = fmaxf(mh[h], m2);
            sh[h] = sh[h] * __expf(mh[h] - mn) + s2 * __expf(m2 - mn);
            mh[h] = mn;
        }
    }
    float inv_s[4];
#pragma unroll
    for (int h = 0; h < 4; h++) {
        mh[h] = __shfl(mh[h], 0);
        sh[h] = __shfl(sh[h], 0);
        inv_s[h] = 1.f / (sh[h] + 1e-16f);
    }

    float4 acc = make_float4(0.f, 0.f, 0.f, 0.f);
    for (int base = beg; base < end; base += 64) {
        int cnt = end - base;
        if (cnt > 64) cnt = 64;
        int my_src = csr[base + (lane < cnt ? lane : 0)];
        float4 asv = *(const float4*)&as_[my_src * 4];
        float e[4] = {asv.x + adn[0], asv.y + adn[1], asv.z + adn[2], asv.w + adn[3]};
        float myal[4];
#pragma unroll
        for (int h = 0; h < 4; h++) {
            float ev = e[h] > 0.f ? e[h] : 0.2f * e[h];
            myal[h] = __expf(ev - mh[h]) * inv_s[h];
        }
        for (int j = 0; j < cnt; j++) {
            int src = __shfl(my_src, j);
            float a0 = __shfl(myal[0], j);
            float a1 = __shfl(myal[1], j);
            float a2 = __shfl(myal[2], j);
            float a3 = __shfl(myal[3], j);
            float al = head < 2 ? (head == 0 ? a0 : a1) : (head == 2 ? a2 : a3);
            float4 v = *(const float4*)&hbuf[(size_t)src * 256 + lane * 4];
            acc.x = fmaf(al, v.x, acc.x);
            acc.y = fmaf(al, v.y, acc.y);
            acc.z = fmaf(al, v.z, acc.z);
            acc.w = fmaf(al, v.w, acc.w);
        }
    }
    float4 bv = *(const float4*)&b[lane * 4];
    acc.x += bv.x; acc.y += bv.y; acc.z += bv.z; acc.w += bv.w;
    acc.x = acc.x > 0.f ? acc.x : __expf(acc.x) - 1.f;
    acc.y = acc.y > 0.f ? acc.y : __expf(acc.y) - 1.f;
    acc.z = acc.z > 0.f ? acc.z : __expf(acc.z) - 1.f;
    acc.w = acc.w > 0.f ? acc.w : __expf(acc.w) - 1.f;
    *(float4*)&out[(size_t)node * 256 + lane * 4] = acc;
}

// ============ fused per-node softmax+agg+bias+ELU, H=1 C=64 ============
__global__ void node_agg1(const int* __restrict__ rowptr, const int* __restrict__ csr,
                          const float* __restrict__ as_, const float* __restrict__ ad_,
                          const float* __restrict__ hbuf, const float* __restrict__ b,
                          float* __restrict__ out, int n) {
    int node = blockIdx.x * 4 + (threadIdx.x >> 6);
    int lane = threadIdx.x & 63;
    if (node >= n) return;
    int beg = rowptr[node], end = rowptr[node + 1];

    float adn = ad_[node];
    float mh = -1e30f, sh = 0.f;
    for (int i = beg + lane; i < end; i += 64) {
        int src = csr[i];
        float ev = as_[src] + adn;
        ev = ev > 0.f ? ev : 0.2f * ev;
        if (ev > mh) {
            sh = sh * __expf(mh - ev) + 1.f;
            mh = ev;
        } else {
            sh += __expf(ev - mh);
        }
    }
#pragma unroll
    for (int off = 32; off > 0; off >>= 1) {
        float m2 = __shfl_down(mh, off);
        float s2 = __shfl_down(sh, off);
        float mn = fmaxf(mh, m2);
        sh = sh * __expf(mh - mn) + s2 * __expf(m2 - mn);
        mh = mn;
    }
    mh = __shfl(mh, 0);
    sh = __shfl(sh, 0);
    float inv_s = 1.f / (sh + 1e-16f);

    float acc = 0.f;
    for (int base = beg; base < end; base += 64) {
        int cnt = end - base;
        if (cnt > 64) cnt = 64;
        int my_src = csr[base + (lane < cnt ? lane : 0)];
        float ev = as_[my_src] + adn;
        ev = ev > 0.f ? ev : 0.2f * ev;
        float myal = __expf(ev - mh) * inv_s;
        for (int j = 0; j < cnt; j++) {
            int src = __shfl(my_src, j);
            float al = __shfl(myal, j);
            acc = fmaf(al, hbuf[(size_t)src * 64 + lane], acc);
        }
    }
    float v = acc + b[lane];
    out[(size_t)node * 64 + lane] = v > 0.f ? v : __expf(v) - 1.f;
}

// ============ fused classifier ============
__global__ void classifier_kernel(const float* __restrict__ z, const float* __restrict__ W3,
                                  const float* __restrict__ b3, const float* __restrict__ W4,
                                  const float* __restrict__ b4, float* __restrict__ out, int n) {
    __shared__ float zt[64][65];
    __shared__ float w3s[64 * 32];
    __shared__ float hid[64][33];
    __shared__ float w4s[64], b3s[32], b4s[2];
    int t = threadIdx.x;
    int r0 = blockIdx.x * 64;
#pragma unroll
    for (int i = 0; i < 16; i++) {
        int j = i * 256 + t;
        int row = j >> 6, col = j & 63;
        int gr = r0 + row;
        zt[row][col] = (gr < n) ? z[(size_t)gr * 64 + col] : 0.f;
    }
#pragma unroll
    for (int i = 0; i < 8; i++) w3s[i * 256 + t] = W3[i * 256 + t];
    if (t < 64) w4s[t] = W4[t];
    if (t < 32) b3s[t] = b3[t];
    if (t < 2) b4s[t] = b4[t];
    __syncthreads();
#pragma unroll
    for (int i = 0; i < 8; i++) {
        int row = (t >> 5) + i * 8;
        int col = t & 31;
        float acc = b3s[col];
#pragma unroll
        for (int k = 0; k < 64; k++) acc += zt[row][k] * w3s[k * 32 + col];
        hid[row][col] = acc > 0.f ? acc : 0.f;
    }
    __syncthreads();
    if (t < 128) {
        int row = t >> 1, c = t & 1;
        int gr = r0 + row;
        if (gr < n) {
            float acc = b4s[c];
#pragma unroll
            for (int k = 0; k < 32; k++) acc += hid[row][k] * w4s[k * 2 + c];
            out[(size_t)gr * 2 + c] = acc;
        }
    }
}

extern "C" void kernel_launch(void* const* d_in, const int* in_sizes, int n_in,
                              void* d_out, int out_size, void* d_ws, size_t ws_size,
                              hipStream_t stream) {
    const float* x      = (const float*)d_in[0];
    const int*   ei     = (const int*)d_in[1];
    const float* W1     = (const float*)d_in[2];
    const float* a_src1 = (const float*)d_in[3];
    const float* a_dst1 = (const float*)d_in[4];
    const float* b1     = (const float*)d_in[5];
    const float* W2     = (const float*)d_in[6];
    const float* a_src2 = (const float*)d_in[7];
    const float* a_dst2 = (const float*)d_in[8];
    const float* b2     = (const float*)d_in[9];
    const float* W3     = (const float*)d_in[10];
    const float* b3     = (const float*)d_in[11];
    const float* W4     = (const float*)d_in[12];
    const float* b4     = (const float*)d_in[13];
    float* out = (float*)d_out;

    const int N = NNODES, E = NEDGES, ET = E + N;
    const int NB = (N + 255) / 256;

    float* ws = (float*)d_ws;
    size_t o = 0;
    float* h1   = ws + o; o += (size_t)N * 256;
    float* out1 = ws + o; o += (size_t)N * 256;
    float* as1  = ws + o; o += (size_t)N * 4;
    float* ad1  = ws + o; o += (size_t)N * 4;
    int* ibase     = (int*)(ws + o);
    int* rowptr    = ibase;
    int* cursor    = rowptr + (N + 1);
    int* blocksums = cursor + N;
    int* csr_src   = blocksums + 256;
    float* h2   = h1;
    float* out2 = h1 + (size_t)N * 64;

    dim3 blk(256);

    // ---- CSR build (shared by both layers) ----
    hipMemsetAsync(cursor, 0, (size_t)N * sizeof(int), stream);
    deg_hist<<<(ET + 255) / 256, blk, 0, stream>>>(ei, cursor, E, ET);
    scan_block<<<NB, blk, 0, stream>>>(cursor, rowptr, blocksums, N);
    scan_sums<<<1, blk, 0, stream>>>(blocksums, NB);
    scan_add<<<NB, blk, 0, stream>>>(rowptr, blocksums, cursor, N, ET);
    csr_scatter<<<(ET + 255) / 256, blk, 0, stream>>>(ei, cursor, csr_src, E, ET);

    // ---- Layer 1 (H=4, C=64) ----
    gemm_tile<128, 8><<<dim3(2, (N + 63) / 64), blk, 0, stream>>>(x, W1, h1, N, 128, 256);
    asad_kernel<4><<<(N + 3) / 4, blk, 0, stream>>>(h1, a_src1, a_dst1, as1, ad1, N);
    node_agg4<<<(N + 3) / 4, blk, 0, stream>>>(rowptr, csr_src, as1, ad1, h1, b1, out1, N);

    // ---- Layer 2 (H=1, C=64) ----
    gemm_tile<64, 4><<<dim3(1, (N + 63) / 64), blk, 0, stream>>>(out1, W2, h2, N, 256, 64);
    asad_kernel<1><<<(N + 3) / 4, blk, 0, stream>>>(h2, a_src2, a_dst2, as1, ad1, N);
    node_agg1<<<(N + 3) / 4, blk, 0, stream>>>(rowptr, csr_src, as1, ad1, h2, b2, out2, N);

    // ---- Classifier ----
    classifier_kernel<<<(N + 63) / 64, blk, 0, stream>>>(out2, W3, b3, W4, b4, out, N);
}

// Round 5
// 428.385 us; speedup vs baseline: 1.8782x; 1.2087x over previous
//
#include <hip/hip_runtime.h>
#include <math.h>

#define NNODES 50000
#define NEDGES 800000

__device__ __forceinline__ unsigned short f2bf(float f) {
    unsigned b = __float_as_uint(f);
    b += 0x7fffu + ((b >> 16) & 1u);  // RNE
    return (unsigned short)(b >> 16);
}
__device__ __forceinline__ float bf_lo(unsigned u) { return __uint_as_float(u << 16); }
__device__ __forceinline__ float bf_hi(unsigned u) { return __uint_as_float(u & 0xffff0000u); }

// ============ canonical fp32 tiled GEMM, dual fp32+bf16 output ============
// BM=64, BK=16; 256 threads as 16(tx) x 16(ty); TM=4 x TN per thread.
template <int BN, int TN>
__global__ __launch_bounds__(256) void gemm_tile(const float* __restrict__ A,
                                                 const float* __restrict__ B,
                                                 float* __restrict__ C,
                                                 unsigned short* __restrict__ Cb,
                                                 int M, int K, int Nc) {
    __shared__ float As[16][68];
    __shared__ float Bs[16][BN];
    int tid = threadIdx.x;
    int m0 = blockIdx.y * 64, n0 = blockIdx.x * BN;
    int tx = tid & 15, ty = tid >> 4;
    float acc[4][TN];
#pragma unroll
    for (int i = 0; i < 4; i++)
#pragma unroll
        for (int j = 0; j < TN; j++) acc[i][j] = 0.f;

    for (int k0 = 0; k0 < K; k0 += 16) {
        {
            int r = tid >> 2, c = (tid & 3) * 4;
            int gr = m0 + r;
            if (gr > M - 1) gr = M - 1;
            float4 v = *(const float4*)&A[(size_t)gr * K + k0 + c];
            As[c][r] = v.x; As[c + 1][r] = v.y; As[c + 2][r] = v.z; As[c + 3][r] = v.w;
        }
#pragma unroll
        for (int f = 0; f < BN / 64; f++) {
            int idx = f * 256 + tid;
            int r = idx / (BN / 4), c = (idx % (BN / 4)) * 4;
            *(float4*)&Bs[r][c] = *(const float4*)&B[(size_t)(k0 + r) * Nc + n0 + c];
        }
        __syncthreads();
#pragma unroll
        for (int kk = 0; kk < 16; kk++) {
            float4 av = *(const float4*)&As[kk][ty * 4];
            float a[4] = {av.x, av.y, av.z, av.w};
            float b[TN];
#pragma unroll
            for (int j4 = 0; j4 < TN / 4; j4++) {
                float4 bv = *(const float4*)&Bs[kk][tx * TN + j4 * 4];
                b[j4 * 4] = bv.x; b[j4 * 4 + 1] = bv.y;
                b[j4 * 4 + 2] = bv.z; b[j4 * 4 + 3] = bv.w;
            }
#pragma unroll
            for (int i = 0; i < 4; i++)
#pragma unroll
                for (int j = 0; j < TN; j++) acc[i][j] = fmaf(a[i], b[j], acc[i][j]);
        }
        __syncthreads();
    }
#pragma unroll
    for (int i = 0; i < 4; i++) {
        int gr = m0 + ty * 4 + i;
        if (gr >= M) continue;
#pragma unroll
        for (int j4 = 0; j4 < TN / 4; j4++) {
            int gc = n0 + tx * TN + j4 * 4;
            float4 v = make_float4(acc[i][j4 * 4], acc[i][j4 * 4 + 1],
                                   acc[i][j4 * 4 + 2], acc[i][j4 * 4 + 3]);
            *(float4*)&C[(size_t)gr * Nc + gc] = v;
            ushort4 s;
            s.x = f2bf(v.x); s.y = f2bf(v.y); s.z = f2bf(v.z); s.w = f2bf(v.w);
            *(ushort4*)&Cb[(size_t)gr * Nc + gc] = s;
        }
    }
}

// ============ per-node attention scalars ============
template <int H>
__global__ void asad_kernel(const float* __restrict__ hbuf, const float* __restrict__ a_src,
                            const float* __restrict__ a_dst, float* __restrict__ as_,
                            float* __restrict__ ad_, int n) {
    int node = blockIdx.x * 4 + (threadIdx.x >> 6);
    int lane = threadIdx.x & 63;
    if (node >= n) return;
#pragma unroll
    for (int hh = 0; hh < H; hh++) {
        float v = hbuf[(size_t)node * (H * 64) + hh * 64 + lane];
        float vs = v * a_src[hh * 64 + lane];
        float vd = v * a_dst[hh * 64 + lane];
#pragma unroll
        for (int off = 32; off > 0; off >>= 1) {
            vs += __shfl_down(vs, off);
            vd += __shfl_down(vd, off);
        }
        if (lane == 0) {
            as_[node * H + hh] = vs;
            ad_[node * H + hh] = vd;
        }
    }
}

// ============ CSR build ============
__global__ void deg_hist(const int* __restrict__ ei, int* __restrict__ deg, int nE, int nT) {
    int idx = blockIdx.x * blockDim.x + threadIdx.x;
    if (idx >= nT) return;
    int dst = (idx < nE) ? ei[nE + idx] : idx - nE;
    atomicAdd(&deg[dst], 1);
}

__global__ void scan_block(const int* __restrict__ deg, int* __restrict__ rowptr,
                           int* __restrict__ blocksums, int n) {
    __shared__ int tmp[256];
    int tid = threadIdx.x;
    int gid = blockIdx.x * 256 + tid;
    int v = (gid < n) ? deg[gid] : 0;
    tmp[tid] = v;
    __syncthreads();
    for (int off = 1; off < 256; off <<= 1) {
        int t = (tid >= off) ? tmp[tid - off] : 0;
        __syncthreads();
        tmp[tid] += t;
        __syncthreads();
    }
    if (gid < n) rowptr[gid] = tmp[tid] - v;
    if (tid == 255) blocksums[blockIdx.x] = tmp[tid];
}

__global__ void scan_sums(int* __restrict__ bs, int nb) {
    __shared__ int tmp[256];
    int tid = threadIdx.x;
    int v = (tid < nb) ? bs[tid] : 0;
    tmp[tid] = v;
    __syncthreads();
    for (int off = 1; off < 256; off <<= 1) {
        int t = (tid >= off) ? tmp[tid - off] : 0;
        __syncthreads();
        tmp[tid] += t;
        __syncthreads();
    }
    if (tid < nb) bs[tid] = tmp[tid] - v;
}

__global__ void scan_add(int* __restrict__ rowptr, const int* __restrict__ bs,
                         int* __restrict__ cursor, int n, int nT) {
    int gid = blockIdx.x * 256 + threadIdx.x;
    if (gid < n) {
        int r = rowptr[gid] + bs[blockIdx.x];
        rowptr[gid] = r;
        cursor[gid] = r;
    }
    if (gid == 0) rowptr[n] = nT;
}

__global__ void csr_scatter(const int* __restrict__ ei, int* __restrict__ cursor,
                            int* __restrict__ csr_src, int nE, int nT) {
    int idx = blockIdx.x * blockDim.x + threadIdx.x;
    if (idx >= nT) return;
    int src, dst;
    if (idx < nE) { src = ei[idx]; dst = ei[nE + idx]; } else { src = dst = idx - nE; }
    int pos = atomicAdd(&cursor[dst], 1);
    csr_src[pos] = src;
}

// ============ fused node softmax+agg+bias+ELU, H=4 C=64, bf16 gather ============
// wave per node; pass B: 2 edges/iter (half-wave each), lane owns 8 channels.
__global__ void node_agg4(const int* __restrict__ rowptr, const int* __restrict__ csr,
                          const float* __restrict__ as_, const float* __restrict__ ad_,
                          const unsigned short* __restrict__ hb, const float* __restrict__ b,
                          float* __restrict__ out, int n) {
    __shared__ float al4[4][64][4];
    __shared__ int sr4[4][64];
    int w = threadIdx.x >> 6;
    int node = blockIdx.x * 4 + w;
    int lane = threadIdx.x & 63;
    if (node >= n) return;
    int beg = rowptr[node], end = rowptr[node + 1];
    int half = lane >> 5;
    int hl = lane & 31;
    int head = hl >> 3;
    int ch0 = hl * 8;

    float4 adv = *(const float4*)&ad_[node * 4];
    float adn[4] = {adv.x, adv.y, adv.z, adv.w};
    float mh[4], sh[4];
#pragma unroll
    for (int h = 0; h < 4; h++) { mh[h] = -1e30f; sh[h] = 0.f; }

    // pass A: online softmax stats
    for (int i = beg + lane; i < end; i += 64) {
        int src = csr[i];
        float4 asv = *(const float4*)&as_[src * 4];
        float e[4] = {asv.x + adn[0], asv.y + adn[1], asv.z + adn[2], asv.w + adn[3]};
#pragma unroll
        for (int h = 0; h < 4; h++) {
            float ev = e[h] > 0.f ? e[h] : 0.2f * e[h];
            if (ev > mh[h]) {
                sh[h] = sh[h] * __expf(mh[h] - ev) + 1.f;
                mh[h] = ev;
            } else {
                sh[h] += __expf(ev - mh[h]);
            }
        }
    }
#pragma unroll
    for (int off = 32; off > 0; off >>= 1) {
#pragma unroll
        for (int h = 0; h < 4; h++) {
            float m2 = __shfl_down(mh[h], off);
            float s2 = __shfl_down(sh[h], off);
            float mn = fmaxf(mh[h], m2);
            sh[h] = sh[h] * __expf(mh[h] - mn) + s2 * __expf(m2 - mn);
            mh[h] = mn;
        }
    }
    float inv_s[4];
#pragma unroll
    for (int h = 0; h < 4; h++) {
        mh[h] = __shfl(mh[h], 0);
        sh[h] = __shfl(sh[h], 0);
        inv_s[h] = 1.f / (sh[h] + 1e-16f);
    }

    // pass B
    float acc[8];
#pragma unroll
    for (int k = 0; k < 8; k++) acc[k] = 0.f;
    for (int base = beg; base < end; base += 64) {
        int cnt = end - base;
        if (cnt > 64) cnt = 64;
        // lane precomputes (src, alpha[4]) for edge base+lane -> wave-private LDS
        int my_src = csr[base + (lane < cnt ? lane : cnt - 1)];
        float4 asv = *(const float4*)&as_[my_src * 4];
        float e[4] = {asv.x + adn[0], asv.y + adn[1], asv.z + adn[2], asv.w + adn[3]};
        float4 mal;
        {
            float t0 = e[0] > 0.f ? e[0] : 0.2f * e[0];
            float t1 = e[1] > 0.f ? e[1] : 0.2f * e[1];
            float t2 = e[2] > 0.f ? e[2] : 0.2f * e[2];
            float t3 = e[3] > 0.f ? e[3] : 0.2f * e[3];
            mal.x = __expf(t0 - mh[0]) * inv_s[0];
            mal.y = __expf(t1 - mh[1]) * inv_s[1];
            mal.z = __expf(t2 - mh[2]) * inv_s[2];
            mal.w = __expf(t3 - mh[3]) * inv_s[3];
        }
        sr4[w][lane] = my_src;
        *(float4*)&al4[w][lane][0] = mal;
        // wave-private LDS: no barrier needed (program-order within wave)
        for (int j = 0; j < cnt; j += 2) {
            int e2 = j + half;
            bool valid = e2 < cnt;
            int esel = valid ? e2 : 0;
            int src = sr4[w][esel];
            float al = al4[w][esel][head];
            if (!valid) al = 0.f;
            uint4 v = *(const uint4*)&hb[(size_t)src * 256 + ch0];
            acc[0] = fmaf(al, bf_lo(v.x), acc[0]);
            acc[1] = fmaf(al, bf_hi(v.x), acc[1]);
            acc[2] = fmaf(al, bf_lo(v.y), acc[2]);
            acc[3] = fmaf(al, bf_hi(v.y), acc[3]);
            acc[4] = fmaf(al, bf_lo(v.z), acc[4]);
            acc[5] = fmaf(al, bf_hi(v.z), acc[5]);
            acc[6] = fmaf(al, bf_lo(v.w), acc[6]);
            acc[7] = fmaf(al, bf_hi(v.w), acc[7]);
        }
    }
    // combine the two halves (same channels)
#pragma unroll
    for (int k = 0; k < 8; k++) acc[k] += __shfl_down(acc[k], 32);
    if (half == 0) {
        float4 b0 = *(const float4*)&b[ch0];
        float4 b1 = *(const float4*)&b[ch0 + 4];
        float o0 = acc[0] + b0.x, o1 = acc[1] + b0.y, o2 = acc[2] + b0.z, o3 = acc[3] + b0.w;
        float o4 = acc[4] + b1.x, o5 = acc[5] + b1.y, o6 = acc[6] + b1.z, o7 = acc[7] + b1.w;
        o0 = o0 > 0.f ? o0 : __expf(o0) - 1.f;
        o1 = o1 > 0.f ? o1 : __expf(o1) - 1.f;
        o2 = o2 > 0.f ? o2 : __expf(o2) - 1.f;
        o3 = o3 > 0.f ? o3 : __expf(o3) - 1.f;
        o4 = o4 > 0.f ? o4 : __expf(o4) - 1.f;
        o5 = o5 > 0.f ? o5 : __expf(o5) - 1.f;
        o6 = o6 > 0.f ? o6 : __expf(o6) - 1.f;
        o7 = o7 > 0.f ? o7 : __expf(o7) - 1.f;
        *(float4*)&out[(size_t)node * 256 + ch0] = make_float4(o0, o1, o2, o3);
        *(float4*)&out[(size_t)node * 256 + ch0 + 4] = make_float4(o4, o5, o6, o7);
    }
}

// ============ fused node softmax+agg+bias+ELU, H=1 C=64, bf16 gather ============
// pass B: 4 edges/iter (quarter-wave each), lane owns 4 channels.
__global__ void node_agg1(const int* __restrict__ rowptr, const int* __restrict__ csr,
                          const float* __restrict__ as_, const float* __restrict__ ad_,
                          const unsigned short* __restrict__ hb, const float* __restrict__ b,
                          float* __restrict__ out, int n) {
    __shared__ float al1[4][64];
    __shared__ int sr1[4][64];
    int w = threadIdx.x >> 6;
    int node = blockIdx.x * 4 + w;
    int lane = threadIdx.x & 63;
    if (node >= n) return;
    int beg = rowptr[node], end = rowptr[node + 1];
    int q = lane >> 4;
    int ql = lane & 15;
    int ch0 = ql * 4;

    float adn = ad_[node];
    float mh = -1e30f, sh = 0.f;
    for (int i = beg + lane; i < end; i += 64) {
        int src = csr[i];
        float ev = as_[src] + adn;
        ev = ev > 0.f ? ev : 0.2f * ev;
        if (ev > mh) {
            sh = sh * __expf(mh - ev) + 1.f;
            mh = ev;
        } else {
            sh += __expf(ev - mh);
        }
    }
#pragma unroll
    for (int off = 32; off > 0; off >>= 1) {
        float m2 = __shfl_down(mh, off);
        float s2 = __shfl_down(sh, off);
        float mn = fmaxf(mh, m2);
        sh = sh * __expf(mh - mn) + s2 * __expf(m2 - mn);
        mh = mn;
    }
    mh = __shfl(mh, 0);
    sh = __shfl(sh, 0);
    float inv_s = 1.f / (sh + 1e-16f);

    float acc[4] = {0.f, 0.f, 0.f, 0.f};
    for (int base = beg; base < end; base += 64) {
        int cnt = end - base;
        if (cnt > 64) cnt = 64;
        int my_src = csr[base + (lane < cnt ? lane : cnt - 1)];
        float ev = as_[my_src] + adn;
        ev = ev > 0.f ? ev : 0.2f * ev;
        float mal = __expf(ev - mh) * inv_s;
        sr1[w][lane] = my_src;
        al1[w][lane] = mal;
        for (int j = 0; j < cnt; j += 4) {
            int e4 = j + q;
            bool valid = e4 < cnt;
            int esel = valid ? e4 : 0;
            int src = sr1[w][esel];
            float al = al1[w][esel];
            if (!valid) al = 0.f;
            uint2 v = *(const uint2*)&hb[(size_t)src * 64 + ch0];
            acc[0] = fmaf(al, bf_lo(v.x), acc[0]);
            acc[1] = fmaf(al, bf_hi(v.x), acc[1]);
            acc[2] = fmaf(al, bf_lo(v.y), acc[2]);
            acc[3] = fmaf(al, bf_hi(v.y), acc[3]);
        }
    }
#pragma unroll
    for (int k = 0; k < 4; k++) {
        acc[k] += __shfl_down(acc[k], 32);
        acc[k] += __shfl_down(acc[k], 16);
    }
    if (q == 0) {
        float4 bv = *(const float4*)&b[ch0];
        float o0 = acc[0] + bv.x, o1 = acc[1] + bv.y, o2 = acc[2] + bv.z, o3 = acc[3] + bv.w;
        o0 = o0 > 0.f ? o0 : __expf(o0) - 1.f;
        o1 = o1 > 0.f ? o1 : __expf(o1) - 1.f;
        o2 = o2 > 0.f ? o2 : __expf(o2) - 1.f;
        o3 = o3 > 0.f ? o3 : __expf(o3) - 1.f;
        *(float4*)&out[(size_t)node * 64 + ch0] = make_float4(o0, o1, o2, o3);
    }
}

// ============ fused classifier ============
__global__ void classifier_kernel(const float* __restrict__ z, const float* __restrict__ W3,
                                  const float* __restrict__ b3, const float* __restrict__ W4,
                                  const float* __restrict__ b4, float* __restrict__ out, int n) {
    __shared__ float zt[64][65];
    __shared__ float w3s[64 * 32];
    __shared__ float hid[64][33];
    __shared__ float w4s[64], b3s[32], b4s[2];
    int t = threadIdx.x;
    int r0 = blockIdx.x * 64;
#pragma unroll
    for (int i = 0; i < 16; i++) {
        int j = i * 256 + t;
        int row = j >> 6, col = j & 63;
        int gr = r0 + row;
        zt[row][col] = (gr < n) ? z[(size_t)gr * 64 + col] : 0.f;
    }
#pragma unroll
    for (int i = 0; i < 8; i++) w3s[i * 256 + t] = W3[i * 256 + t];
    if (t < 64) w4s[t] = W4[t];
    if (t < 32) b3s[t] = b3[t];
    if (t < 2) b4s[t] = b4[t];
    __syncthreads();
#pragma unroll
    for (int i = 0; i < 8; i++) {
        int row = (t >> 5) + i * 8;
        int col = t & 31;
        float acc = b3s[col];
#pragma unroll
        for (int k = 0; k < 64; k++) acc += zt[row][k] * w3s[k * 32 + col];
        hid[row][col] = acc > 0.f ? acc : 0.f;
    }
    __syncthreads();
    if (t < 128) {
        int row = t >> 1, c = t & 1;
        int gr = r0 + row;
        if (gr < n) {
            float acc = b4s[c];
#pragma unroll
            for (int k = 0; k < 32; k++) acc += hid[row][k] * w4s[k * 2 + c];
            out[(size_t)gr * 2 + c] = acc;
        }
    }
}

extern "C" void kernel_launch(void* const* d_in, const int* in_sizes, int n_in,
                              void* d_out, int out_size, void* d_ws, size_t ws_size,
                              hipStream_t stream) {
    const float* x      = (const float*)d_in[0];
    const int*   ei     = (const int*)d_in[1];
    const float* W1     = (const float*)d_in[2];
    const float* a_src1 = (const float*)d_in[3];
    const float* a_dst1 = (const float*)d_in[4];
    const float* b1     = (const float*)d_in[5];
    const float* W2     = (const float*)d_in[6];
    const float* a_src2 = (const float*)d_in[7];
    const float* a_dst2 = (const float*)d_in[8];
    const float* b2     = (const float*)d_in[9];
    const float* W3     = (const float*)d_in[10];
    const float* b3     = (const float*)d_in[11];
    const float* W4     = (const float*)d_in[12];
    const float* b4     = (const float*)d_in[13];
    float* out = (float*)d_out;

    const int N = NNODES, E = NEDGES, ET = E + N;
    const int NB = (N + 255) / 256;

    float* ws = (float*)d_ws;
    size_t o = 0;
    float* h1   = ws + o; o += (size_t)N * 256;
    float* out1 = ws + o; o += (size_t)N * 256;
    float* as1  = ws + o; o += (size_t)N * 4;
    float* ad1  = ws + o; o += (size_t)N * 4;
    unsigned short* h1b = (unsigned short*)(ws + o); o += (size_t)N * 128;  // N*256 bf16
    unsigned short* h2b = (unsigned short*)(ws + o); o += (size_t)N * 32;   // N*64 bf16
    int* rowptr    = (int*)(ws + o);
    int* cursor    = rowptr + (N + 1);
    int* blocksums = cursor + N;
    int* csr_src   = blocksums + 256;
    float* h2   = h1;                       // layer-2 reuse of h1 region
    float* out2 = h1 + (size_t)N * 64;

    dim3 blk(256);

    // ---- CSR build (shared by both layers) ----
    hipMemsetAsync(cursor, 0, (size_t)N * sizeof(int), stream);
    deg_hist<<<(ET + 255) / 256, blk, 0, stream>>>(ei, cursor, E, ET);
    scan_block<<<NB, blk, 0, stream>>>(cursor, rowptr, blocksums, N);
    scan_sums<<<1, blk, 0, stream>>>(blocksums, NB);
    scan_add<<<NB, blk, 0, stream>>>(rowptr, blocksums, cursor, N, ET);
    csr_scatter<<<(ET + 255) / 256, blk, 0, stream>>>(ei, cursor, csr_src, E, ET);

    // ---- Layer 1 (H=4, C=64) ----
    gemm_tile<128, 8><<<dim3(2, (N + 63) / 64), blk, 0, stream>>>(x, W1, h1, h1b, N, 128, 256);
    asad_kernel<4><<<(N + 3) / 4, blk, 0, stream>>>(h1, a_src1, a_dst1, as1, ad1, N);
    node_agg4<<<(N + 3) / 4, blk, 0, stream>>>(rowptr, csr_src, as1, ad1, h1b, b1, out1, N);

    // ---- Layer 2 (H=1, C=64) ----
    gemm_tile<64, 4><<<dim3(1, (N + 63) / 64), blk, 0, stream>>>(out1, W2, h2, h2b, N, 256, 64);
    asad_kernel<1><<<(N + 3) / 4, blk, 0, stream>>>(h2, a_src2, a_dst2, as1, ad1, N);
    node_agg1<<<(N + 3) / 4, blk, 0, stream>>>(rowptr, csr_src, as1, ad1, h2b, b2, out2, N);

    // ---- Classifier ----
    classifier_kernel<<<(N + 63) / 64, blk, 0, stream>>>(out2, W3, b3, W4, b4, out, N);
}

// Round 7
// 414.764 us; speedup vs baseline: 1.9399x; 1.0328x over previous
//
#include <hip/hip_runtime.h>
#include <math.h>

#define NNODES 50000
#define NEDGES 800000

typedef __attribute__((ext_vector_type(8))) short bfrag8;
typedef __attribute__((ext_vector_type(4))) float f32x4;

__device__ __forceinline__ unsigned short f2bf(float f) {
    unsigned b = __float_as_uint(f);
    b += 0x7fffu + ((b >> 16) & 1u);  // RNE
    return (unsigned short)(b >> 16);
}
__device__ __forceinline__ float bf_lo(unsigned u) { return __uint_as_float(u << 16); }
__device__ __forceinline__ float bf_hi(unsigned u) { return __uint_as_float(u & 0xffff0000u); }

// ============ fp32 -> bf16 elementwise convert (float4 -> ushort4) ============
__global__ void cvt_bf16(const float* __restrict__ X, unsigned short* __restrict__ Xb, int n4) {
    int idx = blockIdx.x * blockDim.x + threadIdx.x;
    if (idx >= n4) return;
    float4 v = *(const float4*)&X[idx * 4];
    ushort4 s;
    s.x = f2bf(v.x); s.y = f2bf(v.y); s.z = f2bf(v.z); s.w = f2bf(v.w);
    *(ushort4*)&Xb[idx * 4] = s;
}

// ============ weight prepack: W[K][NC] fp32 -> Wp[n][kf][quad][8] bf16 ============
__global__ void pack_w(const float* __restrict__ W, unsigned short* __restrict__ Wp,
                       int K, int NC) {
    int idx = blockIdx.x * blockDim.x + threadIdx.x;
    if (idx >= K * NC) return;
    int k = idx / NC, n = idx % NC;
    int kf = k >> 5, q = (k >> 3) & 3, j = k & 7;
    Wp[((((size_t)n * (K >> 5) + kf) * 4 + q) << 3) + j] = f2bf(W[idx]);
}

// ============ MFMA bf16 GEMM, no LDS: C[M,NC] = Ab[M,K] @ (Wp packed) ============
// block = 4 waves; wave computes 16 rows x NC cols. M % 16 == 0.
template <int K, int NC>
__global__ __launch_bounds__(256) void gemm_mfma(const unsigned short* __restrict__ Ab,
                                                 const unsigned short* __restrict__ Bp,
                                                 float* __restrict__ C,
                                                 unsigned short* __restrict__ Cb, int M) {
    constexpr int KF = K / 32;
    int wave = threadIdx.x >> 6, lane = threadIdx.x & 63;
    int m0 = (blockIdx.x * 4 + wave) * 16;
    if (m0 >= M) return;
    int quad = lane >> 4, l16 = lane & 15;
    int row = m0 + l16;

    bfrag8 a[KF];
    const unsigned short* arow = Ab + (size_t)row * K + quad * 8;
#pragma unroll
    for (int f = 0; f < KF; f++) a[f] = *(const bfrag8*)(arow + f * 32);

#pragma unroll
    for (int nt = 0; nt < NC / 16; nt++) {
        f32x4 acc = {0.f, 0.f, 0.f, 0.f};
        const unsigned short* bp = Bp + (((size_t)(nt * 16 + l16) * KF) * 4 + quad) * 8;
#pragma unroll
        for (int f = 0; f < KF; f++) {
            bfrag8 bfr = *(const bfrag8*)(bp + (size_t)f * 32);
            acc = __builtin_amdgcn_mfma_f32_16x16x32_bf16(a[f], bfr, acc, 0, 0, 0);
        }
        int colb = nt * 16 + l16;
#pragma unroll
        for (int r = 0; r < 4; r++) {
            int rr = m0 + quad * 4 + r;
            C[(size_t)rr * NC + colb] = acc[r];
            Cb[(size_t)rr * NC + colb] = f2bf(acc[r]);
        }
    }
}

// ============ per-node attention scalars (fp32 h) ============
template <int H>
__global__ void asad_kernel(const float* __restrict__ hbuf, const float* __restrict__ a_src,
                            const float* __restrict__ a_dst, float* __restrict__ as_,
                            float* __restrict__ ad_, int n) {
    int node = blockIdx.x * 4 + (threadIdx.x >> 6);
    int lane = threadIdx.x & 63;
    if (node >= n) return;
#pragma unroll
    for (int hh = 0; hh < H; hh++) {
        float v = hbuf[(size_t)node * (H * 64) + hh * 64 + lane];
        float vs = v * a_src[hh * 64 + lane];
        float vd = v * a_dst[hh * 64 + lane];
#pragma unroll
        for (int off = 32; off > 0; off >>= 1) {
            vs += __shfl_down(vs, off);
            vd += __shfl_down(vd, off);
        }
        if (lane == 0) {
            as_[node * H + hh] = vs;
            ad_[node * H + hh] = vd;
        }
    }
}

// ============ CSR build ============
__global__ void deg_hist(const int* __restrict__ ei, int* __restrict__ deg, int nE, int nT) {
    int idx = blockIdx.x * blockDim.x + threadIdx.x;
    if (idx >= nT) return;
    int dst = (idx < nE) ? ei[nE + idx] : idx - nE;
    atomicAdd(&deg[dst], 1);
}

__global__ void scan_block(const int* __restrict__ deg, int* __restrict__ rowptr,
                           int* __restrict__ blocksums, int n) {
    __shared__ int tmp[256];
    int tid = threadIdx.x;
    int gid = blockIdx.x * 256 + tid;
    int v = (gid < n) ? deg[gid] : 0;
    tmp[tid] = v;
    __syncthreads();
    for (int off = 1; off < 256; off <<= 1) {
        int t = (tid >= off) ? tmp[tid - off] : 0;
        __syncthreads();
        tmp[tid] += t;
        __syncthreads();
    }
    if (gid < n) rowptr[gid] = tmp[tid] - v;
    if (tid == 255) blocksums[blockIdx.x] = tmp[tid];
}

__global__ void scan_sums(int* __restrict__ bs, int nb) {
    __shared__ int tmp[256];
    int tid = threadIdx.x;
    int v = (tid < nb) ? bs[tid] : 0;
    tmp[tid] = v;
    __syncthreads();
    for (int off = 1; off < 256; off <<= 1) {
        int t = (tid >= off) ? tmp[tid - off] : 0;
        __syncthreads();
        tmp[tid] += t;
        __syncthreads();
    }
    if (tid < nb) bs[tid] = tmp[tid] - v;
}

__global__ void scan_add(int* __restrict__ rowptr, const int* __restrict__ bs,
                         int* __restrict__ cursor, int n, int nT) {
    int gid = blockIdx.x * 256 + threadIdx.x;
    if (gid < n) {
        int r = rowptr[gid] + bs[blockIdx.x];
        rowptr[gid] = r;
        cursor[gid] = r;
    }
    if (gid == 0) rowptr[n] = nT;
}

__global__ void csr_scatter(const int* __restrict__ ei, int* __restrict__ cursor,
                            int* __restrict__ csr_src, int nE, int nT) {
    int idx = blockIdx.x * blockDim.x + threadIdx.x;
    if (idx >= nT) return;
    int src, dst;
    if (idx < nE) { src = ei[idx]; dst = ei[nE + idx]; } else { src = dst = idx - nE; }
    int pos = atomicAdd(&cursor[dst], 1);
    csr_src[pos] = src;
}

// ============ fused node softmax+agg+bias+ELU, H=4 C=64, bf16 in/out ============
// wave/node; chunk-0 logits held in registers across the softmax butterfly.
__global__ void node_agg4(const int* __restrict__ rowptr, const int* __restrict__ csr,
                          const float* __restrict__ as_, const float* __restrict__ ad_,
                          const unsigned short* __restrict__ hb, const float* __restrict__ b,
                          unsigned short* __restrict__ outb, int n) {
    __shared__ float al4[4][64][4];
    __shared__ int sr4[4][64];
    int w = threadIdx.x >> 6;
    int node = blockIdx.x * 4 + w;
    int lane = threadIdx.x & 63;
    if (node >= n) return;
    int beg = rowptr[node], end = rowptr[node + 1];
    int cnt = end - beg;
    int cnt0 = cnt < 64 ? cnt : 64;
    bool v0 = lane < cnt0;
    int half = lane >> 5;
    int hl = lane & 31;
    int head = hl >> 3;
    int ch0 = hl * 8;

    float4 adv = *(const float4*)&ad_[node * 4];
    float adn[4] = {adv.x, adv.y, adv.z, adv.w};

    int src0 = csr[beg + (v0 ? lane : 0)];
    float4 asv = *(const float4*)&as_[src0 * 4];
    float ev[4];
    {
        float e0 = asv.x + adn[0], e1 = asv.y + adn[1];
        float e2 = asv.z + adn[2], e3 = asv.w + adn[3];
        ev[0] = e0 > 0.f ? e0 : 0.2f * e0;
        ev[1] = e1 > 0.f ? e1 : 0.2f * e1;
        ev[2] = e2 > 0.f ? e2 : 0.2f * e2;
        ev[3] = e3 > 0.f ? e3 : 0.2f * e3;
    }
    float mh[4], sh[4];
#pragma unroll
    for (int h = 0; h < 4; h++) {
        mh[h] = v0 ? ev[h] : -1e30f;
        sh[h] = v0 ? 1.f : 0.f;
    }
    // rare: edges beyond 64
    for (int i = beg + 64 + lane; i < end; i += 64) {
        int src = csr[i];
        float4 a2 = *(const float4*)&as_[src * 4];
        float e[4] = {a2.x + adn[0], a2.y + adn[1], a2.z + adn[2], a2.w + adn[3]};
#pragma unroll
        for (int h = 0; h < 4; h++) {
            float evv = e[h] > 0.f ? e[h] : 0.2f * e[h];
            if (evv > mh[h]) { sh[h] = sh[h] * __expf(mh[h] - evv) + 1.f; mh[h] = evv; }
            else sh[h] += __expf(evv - mh[h]);
        }
    }
#pragma unroll
    for (int off = 32; off > 0; off >>= 1) {
#pragma unroll
        for (int h = 0; h < 4; h++) {
            float m2 = __shfl_down(mh[h], off);
            float s2 = __shfl_down(sh[h], off);
            float mn = fmaxf(mh[h], m2);
            sh[h] = sh[h] * __expf(mh[h] - mn) + s2 * __expf(m2 - mn);
            mh[h] = mn;
        }
    }
    float inv_s[4];
#pragma unroll
    for (int h = 0; h < 4; h++) {
        mh[h] = __shfl(mh[h], 0);
        sh[h] = __shfl(sh[h], 0);
        inv_s[h] = 1.f / (sh[h] + 1e-16f);
    }
    // chunk-0 alphas straight from registers (invalid lanes -> 0)
    float4 mal;
    mal.x = v0 ? __expf(ev[0] - mh[0]) * inv_s[0] : 0.f;
    mal.y = v0 ? __expf(ev[1] - mh[1]) * inv_s[1] : 0.f;
    mal.z = v0 ? __expf(ev[2] - mh[2]) * inv_s[2] : 0.f;
    mal.w = v0 ? __expf(ev[3] - mh[3]) * inv_s[3] : 0.f;
    sr4[w][lane] = src0;
    *(float4*)&al4[w][lane][0] = mal;

    float acc[8];
#pragma unroll
    for (int k = 0; k < 8; k++) acc[k] = 0.f;
    for (int j = 0; j < cnt0; j += 2) {
        int esel = j + half;
        int src = sr4[w][esel];
        float al = al4[w][esel][head];
        uint4 v = *(const uint4*)&hb[(size_t)src * 256 + ch0];
        acc[0] = fmaf(al, bf_lo(v.x), acc[0]);
        acc[1] = fmaf(al, bf_hi(v.x), acc[1]);
        acc[2] = fmaf(al, bf_lo(v.y), acc[2]);
        acc[3] = fmaf(al, bf_hi(v.y), acc[3]);
        acc[4] = fmaf(al, bf_lo(v.z), acc[4]);
        acc[5] = fmaf(al, bf_hi(v.z), acc[5]);
        acc[6] = fmaf(al, bf_lo(v.w), acc[6]);
        acc[7] = fmaf(al, bf_hi(v.w), acc[7]);
    }
    // rare: chunks beyond 64 (re-gather path)
    for (int base = beg + 64; base < end; base += 64) {
        int c2 = end - base;
        if (c2 > 64) c2 = 64;
        bool vv = lane < c2;
        int msrc = csr[base + (vv ? lane : 0)];
        float4 a2 = *(const float4*)&as_[msrc * 4];
        float e0 = a2.x + adn[0], e1 = a2.y + adn[1], e2 = a2.z + adn[2], e3 = a2.w + adn[3];
        e0 = e0 > 0.f ? e0 : 0.2f * e0;
        e1 = e1 > 0.f ? e1 : 0.2f * e1;
        e2 = e2 > 0.f ? e2 : 0.2f * e2;
        e3 = e3 > 0.f ? e3 : 0.2f * e3;
        float4 m2;
        m2.x = vv ? __expf(e0 - mh[0]) * inv_s[0] : 0.f;
        m2.y = vv ? __expf(e1 - mh[1]) * inv_s[1] : 0.f;
        m2.z = vv ? __expf(e2 - mh[2]) * inv_s[2] : 0.f;
        m2.w = vv ? __expf(e3 - mh[3]) * inv_s[3] : 0.f;
        sr4[w][lane] = msrc;
        *(float4*)&al4[w][lane][0] = m2;
        for (int j = 0; j < c2; j += 2) {
            int esel = j + half;
            int src = sr4[w][esel];
            float al = al4[w][esel][head];
            uint4 v = *(const uint4*)&hb[(size_t)src * 256 + ch0];
            acc[0] = fmaf(al, bf_lo(v.x), acc[0]);
            acc[1] = fmaf(al, bf_hi(v.x), acc[1]);
            acc[2] = fmaf(al, bf_lo(v.y), acc[2]);
            acc[3] = fmaf(al, bf_hi(v.y), acc[3]);
            acc[4] = fmaf(al, bf_lo(v.z), acc[4]);
            acc[5] = fmaf(al, bf_hi(v.z), acc[5]);
            acc[6] = fmaf(al, bf_lo(v.w), acc[6]);
            acc[7] = fmaf(al, bf_hi(v.w), acc[7]);
        }
    }
#pragma unroll
    for (int k = 0; k < 8; k++) acc[k] += __shfl_down(acc[k], 32);
    if (half == 0) {
        float4 b0 = *(const float4*)&b[ch0];
        float4 b1 = *(const float4*)&b[ch0 + 4];
        float o[8] = {acc[0] + b0.x, acc[1] + b0.y, acc[2] + b0.z, acc[3] + b0.w,
                      acc[4] + b1.x, acc[5] + b1.y, acc[6] + b1.z, acc[7] + b1.w};
#pragma unroll
        for (int k = 0; k < 8; k++) o[k] = o[k] > 0.f ? o[k] : __expf(o[k]) - 1.f;
        uint4 p;
        p.x = f2bf(o[0]) | ((unsigned)f2bf(o[1]) << 16);
        p.y = f2bf(o[2]) | ((unsigned)f2bf(o[3]) << 16);
        p.z = f2bf(o[4]) | ((unsigned)f2bf(o[5]) << 16);
        p.w = f2bf(o[6]) | ((unsigned)f2bf(o[7]) << 16);
        *(uint4*)&outb[(size_t)node * 256 + ch0] = p;
    }
}

// ============ fused node softmax+agg+bias+ELU, H=1 C=64, fp32 out ============
__global__ void node_agg1(const int* __restrict__ rowptr, const int* __restrict__ csr,
                          const float* __restrict__ as_, const float* __restrict__ ad_,
                          const unsigned short* __restrict__ hb, const float* __restrict__ b,
                          float* __restrict__ out, int n) {
    __shared__ float al1[4][64];
    __shared__ int sr1[4][64];
    int w = threadIdx.x >> 6;
    int node = blockIdx.x * 4 + w;
    int lane = threadIdx.x & 63;
    if (node >= n) return;
    int beg = rowptr[node], end = rowptr[node + 1];
    int cnt = end - beg;
    int cnt0 = cnt < 64 ? cnt : 64;
    bool v0 = lane < cnt0;
    int q = lane >> 4;
    int ql = lane & 15;
    int ch0 = ql * 4;

    float adn = ad_[node];
    int src0 = csr[beg + (v0 ? lane : 0)];
    float ev = as_[src0] + adn;
    ev = ev > 0.f ? ev : 0.2f * ev;
    float mh = v0 ? ev : -1e30f;
    float sh = v0 ? 1.f : 0.f;
    for (int i = beg + 64 + lane; i < end; i += 64) {
        int src = csr[i];
        float e2 = as_[src] + adn;
        e2 = e2 > 0.f ? e2 : 0.2f * e2;
        if (e2 > mh) { sh = sh * __expf(mh - e2) + 1.f; mh = e2; }
        else sh += __expf(e2 - mh);
    }
#pragma unroll
    for (int off = 32; off > 0; off >>= 1) {
        float m2 = __shfl_down(mh, off);
        float s2 = __shfl_down(sh, off);
        float mn = fmaxf(mh, m2);
        sh = sh * __expf(mh - mn) + s2 * __expf(m2 - mn);
        mh = mn;
    }
    mh = __shfl(mh, 0);
    sh = __shfl(sh, 0);
    float inv_s = 1.f / (sh + 1e-16f);

    float mal = v0 ? __expf(ev - mh) * inv_s : 0.f;
    sr1[w][lane] = src0;
    al1[w][lane] = mal;

    float acc[4] = {0.f, 0.f, 0.f, 0.f};
    for (int j = 0; j < cnt0; j += 4) {
        int esel = j + q;
        int src = sr1[w][esel];
        float al = al1[w][esel];
        uint2 v = *(const uint2*)&hb[(size_t)src * 64 + ch0];
        acc[0] = fmaf(al, bf_lo(v.x), acc[0]);
        acc[1] = fmaf(al, bf_hi(v.x), acc[1]);
        acc[2] = fmaf(al, bf_lo(v.y), acc[2]);
        acc[3] = fmaf(al, bf_hi(v.y), acc[3]);
    }
    for (int base = beg + 64; base < end; base += 64) {
        int c2 = end - base;
        if (c2 > 64) c2 = 64;
        bool vv = lane < c2;
        int msrc = csr[base + (vv ? lane : 0)];
        float e2 = as_[msrc] + adn;
        e2 = e2 > 0.f ? e2 : 0.2f * e2;
        float m2 = vv ? __expf(e2 - mh) * inv_s : 0.f;
        sr1[w][lane] = msrc;
        al1[w][lane] = m2;
        for (int j = 0; j < c2; j += 4) {
            int esel = j + q;
            int src = sr1[w][esel];
            float al = al1[w][esel];
            uint2 v = *(const uint2*)&hb[(size_t)src * 64 + ch0];
            acc[0] = fmaf(al, bf_lo(v.x), acc[0]);
            acc[1] = fmaf(al, bf_hi(v.x), acc[1]);
            acc[2] = fmaf(al, bf_lo(v.y), acc[2]);
            acc[3] = fmaf(al, bf_hi(v.y), acc[3]);
        }
    }
#pragma unroll
    for (int k = 0; k < 4; k++) {
        acc[k] += __shfl_down(acc[k], 32);
        acc[k] += __shfl_down(acc[k], 16);
    }
    if (q == 0) {
        float4 bv = *(const float4*)&b[ch0];
        float o0 = acc[0] + bv.x, o1 = acc[1] + bv.y, o2 = acc[2] + bv.z, o3 = acc[3] + bv.w;
        o0 = o0 > 0.f ? o0 : __expf(o0) - 1.f;
        o1 = o1 > 0.f ? o1 : __expf(o1) - 1.f;
        o2 = o2 > 0.f ? o2 : __expf(o2) - 1.f;
        o3 = o3 > 0.f ? o3 : __expf(o3) - 1.f;
        *(float4*)&out[(size_t)node * 64 + ch0] = make_float4(o0, o1, o2, o3);
    }
}

// ============ fused classifier ============
__global__ void classifier_kernel(const float* __restrict__ z, const float* __restrict__ W3,
                                  const float* __restrict__ b3, const float* __restrict__ W4,
                                  const float* __restrict__ b4, float* __restrict__ out, int n) {
    __shared__ float zt[64][65];
    __shared__ float w3s[64 * 32];
    __shared__ float hid[64][33];
    __shared__ float w4s[64], b3s[32], b4s[2];
    int t = threadIdx.x;
    int r0 = blockIdx.x * 64;
#pragma unroll
    for (int i = 0; i < 16; i++) {
        int j = i * 256 + t;
        int row = j >> 6, col = j & 63;
        int gr = r0 + row;
        zt[row][col] = (gr < n) ? z[(size_t)gr * 64 + col] : 0.f;
    }
#pragma unroll
    for (int i = 0; i < 8; i++) w3s[i * 256 + t] = W3[i * 256 + t];
    if (t < 64) w4s[t] = W4[t];
    if (t < 32) b3s[t] = b3[t];
    if (t < 2) b4s[t] = b4[t];
    __syncthreads();
#pragma unroll
    for (int i = 0; i < 8; i++) {
        int row = (t >> 5) + i * 8;
        int col = t & 31;
        float acc = b3s[col];
#pragma unroll
        for (int k = 0; k < 64; k++) acc += zt[row][k] * w3s[k * 32 + col];
        hid[row][col] = acc > 0.f ? acc : 0.f;
    }
    __syncthreads();
    if (t < 128) {
        int row = t >> 1, c = t & 1;
        int gr = r0 + row;
        if (gr < n) {
            float acc = b4s[c];
#pragma unroll
            for (int k = 0; k < 32; k++) acc += hid[row][k] * w4s[k * 2 + c];
            out[(size_t)gr * 2 + c] = acc;
        }
    }
}

extern "C" void kernel_launch(void* const* d_in, const int* in_sizes, int n_in,
                              void* d_out, int out_size, void* d_ws, size_t ws_size,
                              hipStream_t stream) {
    const float* x      = (const float*)d_in[0];
    const int*   ei     = (const int*)d_in[1];
    const float* W1     = (const float*)d_in[2];
    const float* a_src1 = (const float*)d_in[3];
    const float* a_dst1 = (const float*)d_in[4];
    const float* b1     = (const float*)d_in[5];
    const float* W2     = (const float*)d_in[6];
    const float* a_src2 = (const float*)d_in[7];
    const float* a_dst2 = (const float*)d_in[8];
    const float* b2     = (const float*)d_in[9];
    const float* W3     = (const float*)d_in[10];
    const float* b3     = (const float*)d_in[11];
    const float* W4     = (const float*)d_in[12];
    const float* b4     = (const float*)d_in[13];
    float* out = (float*)d_out;

    const int N = NNODES, E = NEDGES, ET = E + N;
    const int NB = (N + 255) / 256;

    float* ws = (float*)d_ws;
    // region A: h1 fp32 [N*256]; later h2 [N*64] @0, out2 [N*64] @N*64,
    //           out1b bf16 [N*256 ushort] @ float offset N*128
    float* h1   = ws;
    float* h2   = ws;
    float* out2 = ws + (size_t)N * 64;
    unsigned short* out1b = (unsigned short*)(ws + (size_t)N * 128);
    size_t o = (size_t)N * 256;
    float* as1 = ws + o; o += (size_t)N * 4;
    float* ad1 = ws + o; o += (size_t)N * 4;
    unsigned short* h1b = (unsigned short*)(ws + o); o += (size_t)N * 128;  // N*256 bf16
    unsigned short* h2b = (unsigned short*)(ws + o); o += (size_t)N * 32;   // N*64 bf16
    unsigned short* xb  = (unsigned short*)(ws + o); o += (size_t)N * 64;   // N*128 bf16
    unsigned short* W1p = (unsigned short*)(ws + o); o += 16384;  // 128*256 bf16 = 32768 ushort
    unsigned short* W2p = (unsigned short*)(ws + o); o += 8192;   // 256*64 bf16  = 16384 ushort
    int* rowptr    = (int*)(ws + o);
    int* cursor    = rowptr + (N + 1);
    int* blocksums = cursor + N;
    int* csr_src   = blocksums + 256;

    dim3 blk(256);

    // ---- prep: bf16 conversions + weight prepack ----
    cvt_bf16<<<((size_t)N * 128 / 4 + 255) / 256, blk, 0, stream>>>(x, xb, N * 128 / 4);
    pack_w<<<(128 * 256 + 255) / 256, blk, 0, stream>>>(W1, W1p, 128, 256);
    pack_w<<<(256 * 64 + 255) / 256, blk, 0, stream>>>(W2, W2p, 256, 64);

    // ---- CSR build (shared by both layers) ----
    hipMemsetAsync(cursor, 0, (size_t)N * sizeof(int), stream);
    deg_hist<<<(ET + 255) / 256, blk, 0, stream>>>(ei, cursor, E, ET);
    scan_block<<<NB, blk, 0, stream>>>(cursor, rowptr, blocksums, N);
    scan_sums<<<1, blk, 0, stream>>>(blocksums, NB);
    scan_add<<<NB, blk, 0, stream>>>(rowptr, blocksums, cursor, N, ET);
    csr_scatter<<<(ET + 255) / 256, blk, 0, stream>>>(ei, cursor, csr_src, E, ET);

    // ---- Layer 1 (H=4, C=64) ----
    gemm_mfma<128, 256><<<(N + 63) / 64, blk, 0, stream>>>(xb, W1p, h1, h1b, N);
    asad_kernel<4><<<(N + 3) / 4, blk, 0, stream>>>(h1, a_src1, a_dst1, as1, ad1, N);
    node_agg4<<<(N + 3) / 4, blk, 0, stream>>>(rowptr, csr_src, as1, ad1, h1b, b1, out1b, N);

    // ---- Layer 2 (H=1, C=64) ----
    gemm_mfma<256, 64><<<(N + 63) / 64, blk, 0, stream>>>(out1b, W2p, h2, h2b, N);
    asad_kernel<1><<<(N + 3) / 4, blk, 0, stream>>>(h2, a_src2, a_dst2, as1, ad1, N);
    node_agg1<<<(N + 3) / 4, blk, 0, stream>>>(rowptr, csr_src, as1, ad1, h2b, b2, out2, N);

    // ---- Classifier ----
    classifier_kernel<<<(N + 63) / 64, blk, 0, stream>>>(out2, W3, b3, W4, b4, out, N);
}

// Round 8
// 364.707 us; speedup vs baseline: 2.2062x; 1.1373x over previous
//
#include <hip/hip_runtime.h>
#include <math.h>

#define NNODES 50000
#define NEDGES 800000

typedef __attribute__((ext_vector_type(8))) short bfrag8;
typedef __attribute__((ext_vector_type(4))) float f32x4;

__device__ __forceinline__ unsigned short f2bf(float f) {
    unsigned b = __float_as_uint(f);
    b += 0x7fffu + ((b >> 16) & 1u);  // RNE
    return (unsigned short)(b >> 16);
}
__device__ __forceinline__ float bf_lo(unsigned u) { return __uint_as_float(u << 16); }
__device__ __forceinline__ float bf_hi(unsigned u) { return __uint_as_float(u & 0xffff0000u); }

__device__ __forceinline__ void pack_one(const float* W, unsigned short* Wp, int K, int NC,
                                         int idx) {
    int k = idx / NC, n = idx % NC;
    int kf = k >> 5, q = (k >> 3) & 3, j = k & 7;
    Wp[((((size_t)n * (K >> 5) + kf) * 4 + q) << 3) + j] = f2bf(W[idx]);
}

// ============ merged prep: x->bf16, pack W1, pack W2, zero cursor ============
__global__ void prep_kernel(const float* __restrict__ x, unsigned short* __restrict__ xb,
                            const float* __restrict__ W1, unsigned short* __restrict__ W1p,
                            const float* __restrict__ W2, unsigned short* __restrict__ W2p,
                            int* __restrict__ cursor, int ncvt4, int n) {
    int idx = blockIdx.x * blockDim.x + threadIdx.x;
    if (idx < ncvt4) {
        float4 v = *(const float4*)&x[idx * 4];
        ushort4 s;
        s.x = f2bf(v.x); s.y = f2bf(v.y); s.z = f2bf(v.z); s.w = f2bf(v.w);
        *(ushort4*)&xb[idx * 4] = s;
    }
    if (idx < 128 * 256) pack_one(W1, W1p, 128, 256, idx);
    if (idx < 256 * 64) pack_one(W2, W2p, 256, 64, idx);
    if (idx < n) cursor[idx] = 0;
}

// ============ MFMA bf16 GEMM fused with as/ad computation ============
// block = 4 waves; wave computes 16 rows x NC cols; writes bf16 C + as_/ad_.
template <int K, int H>
__global__ __launch_bounds__(256) void gemm_asad(const unsigned short* __restrict__ Ab,
                                                 const unsigned short* __restrict__ Bp,
                                                 const float* __restrict__ a_src,
                                                 const float* __restrict__ a_dst,
                                                 unsigned short* __restrict__ Cb,
                                                 float* __restrict__ as_,
                                                 float* __restrict__ ad_, int M) {
    constexpr int KF = K / 32;
    constexpr int NC = H * 64;
    int wave = threadIdx.x >> 6, lane = threadIdx.x & 63;
    int m0 = (blockIdx.x * 4 + wave) * 16;
    if (m0 >= M) return;
    int quad = lane >> 4, l16 = lane & 15;
    int row = m0 + l16;

    bfrag8 a[KF];
    const unsigned short* arow = Ab + (size_t)row * K + quad * 8;
#pragma unroll
    for (int f = 0; f < KF; f++) a[f] = *(const bfrag8*)(arow + f * 32);

    float ps[4] = {0.f, 0.f, 0.f, 0.f};
    float pd[4] = {0.f, 0.f, 0.f, 0.f};
#pragma unroll
    for (int nt = 0; nt < NC / 16; nt++) {
        f32x4 acc = {0.f, 0.f, 0.f, 0.f};
        const unsigned short* bp = Bp + (((size_t)(nt * 16 + l16) * KF) * 4 + quad) * 8;
#pragma unroll
        for (int f = 0; f < KF; f++) {
            bfrag8 bfr = *(const bfrag8*)(bp + (size_t)f * 32);
            acc = __builtin_amdgcn_mfma_f32_16x16x32_bf16(a[f], bfr, acc, 0, 0, 0);
        }
        int col = nt * 16 + l16;
        float avs = a_src[col], avd = a_dst[col];
#pragma unroll
        for (int r = 0; r < 4; r++) {
            ps[r] = fmaf(acc[r], avs, ps[r]);
            pd[r] = fmaf(acc[r], avd, pd[r]);
            Cb[(size_t)(m0 + quad * 4 + r) * NC + col] = f2bf(acc[r]);
        }
        if ((nt & 3) == 3) {
            int head = nt >> 2;
#pragma unroll
            for (int off = 1; off < 16; off <<= 1) {
#pragma unroll
                for (int r = 0; r < 4; r++) {
                    ps[r] += __shfl_xor(ps[r], off);
                    pd[r] += __shfl_xor(pd[r], off);
                }
            }
            if (l16 == 0) {
#pragma unroll
                for (int r = 0; r < 4; r++) {
                    as_[(size_t)(m0 + quad * 4 + r) * H + head] = ps[r];
                    ad_[(size_t)(m0 + quad * 4 + r) * H + head] = pd[r];
                }
            }
#pragma unroll
            for (int r = 0; r < 4; r++) { ps[r] = 0.f; pd[r] = 0.f; }
        }
    }
}

// ============ CSR build ============
__global__ void deg_hist(const int* __restrict__ ei, int* __restrict__ deg, int nE, int nT) {
    int idx = blockIdx.x * blockDim.x + threadIdx.x;
    if (idx >= nT) return;
    int dst = (idx < nE) ? ei[nE + idx] : idx - nE;
    atomicAdd(&deg[dst], 1);
}

__global__ void scan_block(const int* __restrict__ deg, int* __restrict__ rowptr,
                           int* __restrict__ blocksums, int n) {
    __shared__ int tmp[256];
    int tid = threadIdx.x;
    int gid = blockIdx.x * 256 + tid;
    int v = (gid < n) ? deg[gid] : 0;
    tmp[tid] = v;
    __syncthreads();
    for (int off = 1; off < 256; off <<= 1) {
        int t = (tid >= off) ? tmp[tid - off] : 0;
        __syncthreads();
        tmp[tid] += t;
        __syncthreads();
    }
    if (gid < n) rowptr[gid] = tmp[tid] - v;
    if (tid == 255) blocksums[blockIdx.x] = tmp[tid];
}

__global__ void scan_sums(int* __restrict__ bs, int nb) {
    __shared__ int tmp[256];
    int tid = threadIdx.x;
    int v = (tid < nb) ? bs[tid] : 0;
    tmp[tid] = v;
    __syncthreads();
    for (int off = 1; off < 256; off <<= 1) {
        int t = (tid >= off) ? tmp[tid - off] : 0;
        __syncthreads();
        tmp[tid] += t;
        __syncthreads();
    }
    if (tid < nb) bs[tid] = tmp[tid] - v;
}

__global__ void scan_add(int* __restrict__ rowptr, const int* __restrict__ bs,
                         int* __restrict__ cursor, int n, int nT) {
    int gid = blockIdx.x * 256 + threadIdx.x;
    if (gid < n) {
        int r = rowptr[gid] + bs[blockIdx.x];
        rowptr[gid] = r;
        cursor[gid] = r;
    }
    if (gid == 0) rowptr[n] = nT;
}

__global__ void csr_scatter(const int* __restrict__ ei, int* __restrict__ cursor,
                            int* __restrict__ csr_src, int nE, int nT) {
    int idx = blockIdx.x * blockDim.x + threadIdx.x;
    if (idx >= nT) return;
    int src, dst;
    if (idx < nE) { src = ei[idx]; dst = ei[nE + idx]; } else { src = dst = idx - nE; }
    int pos = atomicAdd(&cursor[dst], 1);
    csr_src[pos] = src;
}

// ============ fused node softmax+agg+bias+ELU, H=4 C=64, depth-4 pipeline ============
__global__ void node_agg4(const int* __restrict__ rowptr, const int* __restrict__ csr,
                          const float* __restrict__ as_, const float* __restrict__ ad_,
                          const unsigned short* __restrict__ hb, const float* __restrict__ b,
                          unsigned short* __restrict__ outb, int n) {
    __shared__ float alf[4][4][64];
    __shared__ int srs[4][64];
    int w = threadIdx.x >> 6;
    int node = blockIdx.x * 4 + w;
    int lane = threadIdx.x & 63;
    if (node >= n) return;
    int beg = rowptr[node], end = rowptr[node + 1];
    int cnt = end - beg;
    int cnt0 = cnt < 64 ? cnt : 64;
    bool v0 = lane < cnt0;
    int half = lane >> 5;
    int hl = lane & 31;
    int head = hl >> 3;
    int ch0 = hl * 8;

    float4 adv = *(const float4*)&ad_[node * 4];
    float adn[4] = {adv.x, adv.y, adv.z, adv.w};

    int src0 = csr[beg + (v0 ? lane : 0)];
    float4 asv = *(const float4*)&as_[src0 * 4];
    float ev[4];
    {
        float e0 = asv.x + adn[0], e1 = asv.y + adn[1];
        float e2 = asv.z + adn[2], e3 = asv.w + adn[3];
        ev[0] = e0 > 0.f ? e0 : 0.2f * e0;
        ev[1] = e1 > 0.f ? e1 : 0.2f * e1;
        ev[2] = e2 > 0.f ? e2 : 0.2f * e2;
        ev[3] = e3 > 0.f ? e3 : 0.2f * e3;
    }
    float mh[4], sh[4];
#pragma unroll
    for (int h = 0; h < 4; h++) {
        mh[h] = v0 ? ev[h] : -1e30f;
        sh[h] = v0 ? 1.f : 0.f;
    }
    for (int i = beg + 64 + lane; i < end; i += 64) {
        int src = csr[i];
        float4 a2 = *(const float4*)&as_[src * 4];
        float e[4] = {a2.x + adn[0], a2.y + adn[1], a2.z + adn[2], a2.w + adn[3]};
#pragma unroll
        for (int h = 0; h < 4; h++) {
            float evv = e[h] > 0.f ? e[h] : 0.2f * e[h];
            if (evv > mh[h]) { sh[h] = sh[h] * __expf(mh[h] - evv) + 1.f; mh[h] = evv; }
            else sh[h] += __expf(evv - mh[h]);
        }
    }
#pragma unroll
    for (int off = 32; off > 0; off >>= 1) {
#pragma unroll
        for (int h = 0; h < 4; h++) {
            float m2 = __shfl_down(mh[h], off);
            float s2 = __shfl_down(sh[h], off);
            float mn = fmaxf(mh[h], m2);
            sh[h] = sh[h] * __expf(mh[h] - mn) + s2 * __expf(m2 - mn);
            mh[h] = mn;
        }
    }
    float inv_s[4];
#pragma unroll
    for (int h = 0; h < 4; h++) {
        mh[h] = __shfl(mh[h], 0);
        sh[h] = __shfl(sh[h], 0);
        inv_s[h] = 1.f / (sh[h] + 1e-16f);
    }
    srs[w][lane] = src0;
    alf[w][0][lane] = v0 ? __expf(ev[0] - mh[0]) * inv_s[0] : 0.f;
    alf[w][1][lane] = v0 ? __expf(ev[1] - mh[1]) * inv_s[1] : 0.f;
    alf[w][2][lane] = v0 ? __expf(ev[2] - mh[2]) * inv_s[2] : 0.f;
    alf[w][3][lane] = v0 ? __expf(ev[3] - mh[3]) * inv_s[3] : 0.f;

    float acc[8];
#pragma unroll
    for (int k = 0; k < 8; k++) acc[k] = 0.f;

    int iters = (cnt0 + 1) >> 1;
    int iters4 = (iters + 3) & ~3;  // pad: extra iters have alpha=0, dup-src addr

#define LD4(vk, ak, t)                                              \
    {                                                               \
        int e_ = 2 * (t) + half;                                    \
        int s_ = srs[w][e_];                                        \
        ak = alf[w][head][e_];                                      \
        vk = *(const uint4*)&hb[(size_t)s_ * 256 + ch0];            \
    }
#define FMA8(ak, vk)                                                \
    {                                                               \
        acc[0] = fmaf(ak, bf_lo(vk.x), acc[0]);                     \
        acc[1] = fmaf(ak, bf_hi(vk.x), acc[1]);                     \
        acc[2] = fmaf(ak, bf_lo(vk.y), acc[2]);                     \
        acc[3] = fmaf(ak, bf_hi(vk.y), acc[3]);                     \
        acc[4] = fmaf(ak, bf_lo(vk.z), acc[4]);                     \
        acc[5] = fmaf(ak, bf_hi(vk.z), acc[5]);                     \
        acc[6] = fmaf(ak, bf_lo(vk.w), acc[6]);                     \
        acc[7] = fmaf(ak, bf_hi(vk.w), acc[7]);                     \
    }

    uint4 q0, q1, q2, q3;
    float a0, a1, a2, a3;
    LD4(q0, a0, 0) LD4(q1, a1, 1) LD4(q2, a2, 2) LD4(q3, a3, 3)
    int c = 0;
    for (; c < iters4 - 4; c += 4) {
        FMA8(a0, q0) LD4(q0, a0, c + 4)
        FMA8(a1, q1) LD4(q1, a1, c + 5)
        FMA8(a2, q2) LD4(q2, a2, c + 6)
        FMA8(a3, q3) LD4(q3, a3, c + 7)
    }
    FMA8(a0, q0) FMA8(a1, q1) FMA8(a2, q2) FMA8(a3, q3)

    // rare: chunks beyond 64 edges
    for (int base = beg + 64; base < end; base += 64) {
        int c2 = end - base;
        if (c2 > 64) c2 = 64;
        bool vv = lane < c2;
        int msrc = csr[base + (vv ? lane : 0)];
        float4 a2v = *(const float4*)&as_[msrc * 4];
        float e0 = a2v.x + adn[0], e1 = a2v.y + adn[1];
        float e2 = a2v.z + adn[2], e3 = a2v.w + adn[3];
        e0 = e0 > 0.f ? e0 : 0.2f * e0;
        e1 = e1 > 0.f ? e1 : 0.2f * e1;
        e2 = e2 > 0.f ? e2 : 0.2f * e2;
        e3 = e3 > 0.f ? e3 : 0.2f * e3;
        srs[w][lane] = msrc;
        alf[w][0][lane] = vv ? __expf(e0 - mh[0]) * inv_s[0] : 0.f;
        alf[w][1][lane] = vv ? __expf(e1 - mh[1]) * inv_s[1] : 0.f;
        alf[w][2][lane] = vv ? __expf(e2 - mh[2]) * inv_s[2] : 0.f;
        alf[w][3][lane] = vv ? __expf(e3 - mh[3]) * inv_s[3] : 0.f;
        for (int j = 0; j < c2; j += 2) {
            int e_ = j + half;
            int s_ = srs[w][e_];
            float al = alf[w][head][e_];
            uint4 v = *(const uint4*)&hb[(size_t)s_ * 256 + ch0];
            FMA8(al, v)
        }
    }
#pragma unroll
    for (int k = 0; k < 8; k++) acc[k] += __shfl_down(acc[k], 32);
    if (half == 0) {
        float4 b0 = *(const float4*)&b[ch0];
        float4 b1 = *(const float4*)&b[ch0 + 4];
        float o[8] = {acc[0] + b0.x, acc[1] + b0.y, acc[2] + b0.z, acc[3] + b0.w,
                      acc[4] + b1.x, acc[5] + b1.y, acc[6] + b1.z, acc[7] + b1.w};
#pragma unroll
        for (int k = 0; k < 8; k++) o[k] = o[k] > 0.f ? o[k] : __expf(o[k]) - 1.f;
        uint4 p;
        p.x = f2bf(o[0]) | ((unsigned)f2bf(o[1]) << 16);
        p.y = f2bf(o[2]) | ((unsigned)f2bf(o[3]) << 16);
        p.z = f2bf(o[4]) | ((unsigned)f2bf(o[5]) << 16);
        p.w = f2bf(o[6]) | ((unsigned)f2bf(o[7]) << 16);
        *(uint4*)&outb[(size_t)node * 256 + ch0] = p;
    }
#undef LD4
#undef FMA8
}

// ============ fused node softmax+agg+bias+ELU, H=1 C=64, depth-4 pipeline ============
__global__ void node_agg1(const int* __restrict__ rowptr, const int* __restrict__ csr,
                          const float* __restrict__ as_, const float* __restrict__ ad_,
                          const unsigned short* __restrict__ hb, const float* __restrict__ b,
                          float* __restrict__ out, int n) {
    __shared__ float alf[4][64];
    __shared__ int srs[4][64];
    int w = threadIdx.x >> 6;
    int node = blockIdx.x * 4 + w;
    int lane = threadIdx.x & 63;
    if (node >= n) return;
    int beg = rowptr[node], end = rowptr[node + 1];
    int cnt = end - beg;
    int cnt0 = cnt < 64 ? cnt : 64;
    bool v0 = lane < cnt0;
    int q = lane >> 4;
    int ql = lane & 15;
    int ch0 = ql * 4;

    float adn = ad_[node];
    int src0 = csr[beg + (v0 ? lane : 0)];
    float ev = as_[src0] + adn;
    ev = ev > 0.f ? ev : 0.2f * ev;
    float mh = v0 ? ev : -1e30f;
    float sh = v0 ? 1.f : 0.f;
    for (int i = beg + 64 + lane; i < end; i += 64) {
        int src = csr[i];
        float e2 = as_[src] + adn;
        e2 = e2 > 0.f ? e2 : 0.2f * e2;
        if (e2 > mh) { sh = sh * __expf(mh - e2) + 1.f; mh = e2; }
        else sh += __expf(e2 - mh);
    }
#pragma unroll
    for (int off = 32; off > 0; off >>= 1) {
        float m2 = __shfl_down(mh, off);
        float s2 = __shfl_down(sh, off);
        float mn = fmaxf(mh, m2);
        sh = sh * __expf(mh - mn) + s2 * __expf(m2 - mn);
        mh = mn;
    }
    mh = __shfl(mh, 0);
    sh = __shfl(sh, 0);
    float inv_s = 1.f / (sh + 1e-16f);

    srs[w][lane] = src0;
    alf[w][lane] = v0 ? __expf(ev - mh) * inv_s : 0.f;

    float acc[4] = {0.f, 0.f, 0.f, 0.f};
    int iters = (cnt0 + 3) >> 2;
    int iters4 = (iters + 3) & ~3;

#define LD2(vk, ak, t)                                              \
    {                                                               \
        int e_ = 4 * (t) + q;                                       \
        int s_ = srs[w][e_];                                        \
        ak = alf[w][e_];                                            \
        vk = *(const uint2*)&hb[(size_t)s_ * 64 + ch0];             \
    }
#define FMA4(ak, vk)                                                \
    {                                                               \
        acc[0] = fmaf(ak, bf_lo(vk.x), acc[0]);                     \
        acc[1] = fmaf(ak, bf_hi(vk.x), acc[1]);                     \
        acc[2] = fmaf(ak, bf_lo(vk.y), acc[2]);                     \
        acc[3] = fmaf(ak, bf_hi(vk.y), acc[3]);                     \
    }

    uint2 q0, q1, q2, q3;
    float a0, a1, a2, a3;
    LD2(q0, a0, 0) LD2(q1, a1, 1) LD2(q2, a2, 2) LD2(q3, a3, 3)
    int c = 0;
    for (; c < iters4 - 4; c += 4) {
        FMA4(a0, q0) LD2(q0, a0, c + 4)
        FMA4(a1, q1) LD2(q1, a1, c + 5)
        FMA4(a2, q2) LD2(q2, a2, c + 6)
        FMA4(a3, q3) LD2(q3, a3, c + 7)
    }
    FMA4(a0, q0) FMA4(a1, q1) FMA4(a2, q2) FMA4(a3, q3)

    for (int base = beg + 64; base < end; base += 64) {
        int c2 = end - base;
        if (c2 > 64) c2 = 64;
        bool vv = lane < c2;
        int msrc = csr[base + (vv ? lane : 0)];
        float e2 = as_[msrc] + adn;
        e2 = e2 > 0.f ? e2 : 0.2f * e2;
        srs[w][lane] = msrc;
        alf[w][lane] = vv ? __expf(e2 - mh) * inv_s : 0.f;
        for (int j = 0; j < c2; j += 4) {
            int e_ = j + q;
            int s_ = srs[w][e_];
            float al = alf[w][e_];
            uint2 v = *(const uint2*)&hb[(size_t)s_ * 64 + ch0];
            FMA4(al, v)
        }
    }
#pragma unroll
    for (int k = 0; k < 4; k++) {
        acc[k] += __shfl_down(acc[k], 32);
        acc[k] += __shfl_down(acc[k], 16);
    }
    if (q == 0) {
        float4 bv = *(const float4*)&b[ch0];
        float o0 = acc[0] + bv.x, o1 = acc[1] + bv.y, o2 = acc[2] + bv.z, o3 = acc[3] + bv.w;
        o0 = o0 > 0.f ? o0 : __expf(o0) - 1.f;
        o1 = o1 > 0.f ? o1 : __expf(o1) - 1.f;
        o2 = o2 > 0.f ? o2 : __expf(o2) - 1.f;
        o3 = o3 > 0.f ? o3 : __expf(o3) - 1.f;
        *(float4*)&out[(size_t)node * 64 + ch0] = make_float4(o0, o1, o2, o3);
    }
#undef LD2
#undef FMA4
}

// ============ fused classifier ============
__global__ void classifier_kernel(const float* __restrict__ z, const float* __restrict__ W3,
                                  const float* __restrict__ b3, const float* __restrict__ W4,
                                  const float* __restrict__ b4, float* __restrict__ out, int n) {
    __shared__ float zt[64][65];
    __shared__ float w3s[64 * 32];
    __shared__ float hid[64][33];
    __shared__ float w4s[64], b3s[32], b4s[2];
    int t = threadIdx.x;
    int r0 = blockIdx.x * 64;
#pragma unroll
    for (int i = 0; i < 16; i++) {
        int j = i * 256 + t;
        int row = j >> 6, col = j & 63;
        int gr = r0 + row;
        zt[row][col] = (gr < n) ? z[(size_t)gr * 64 + col] : 0.f;
    }
#pragma unroll
    for (int i = 0; i < 8; i++) w3s[i * 256 + t] = W3[i * 256 + t];
    if (t < 64) w4s[t] = W4[t];
    if (t < 32) b3s[t] = b3[t];
    if (t < 2) b4s[t] = b4[t];
    __syncthreads();
#pragma unroll
    for (int i = 0; i < 8; i++) {
        int row = (t >> 5) + i * 8;
        int col = t & 31;
        float acc = b3s[col];
#pragma unroll
        for (int k = 0; k < 64; k++) acc += zt[row][k] * w3s[k * 32 + col];
        hid[row][col] = acc > 0.f ? acc : 0.f;
    }
    __syncthreads();
    if (t < 128) {
        int row = t >> 1, c = t & 1;
        int gr = r0 + row;
        if (gr < n) {
            float acc = b4s[c];
#pragma unroll
            for (int k = 0; k < 32; k++) acc += hid[row][k] * w4s[k * 2 + c];
            out[(size_t)gr * 2 + c] = acc;
        }
    }
}

extern "C" void kernel_launch(void* const* d_in, const int* in_sizes, int n_in,
                              void* d_out, int out_size, void* d_ws, size_t ws_size,
                              hipStream_t stream) {
    const float* x      = (const float*)d_in[0];
    const int*   ei     = (const int*)d_in[1];
    const float* W1     = (const float*)d_in[2];
    const float* a_src1 = (const float*)d_in[3];
    const float* a_dst1 = (const float*)d_in[4];
    const float* b1     = (const float*)d_in[5];
    const float* W2     = (const float*)d_in[6];
    const float* a_src2 = (const float*)d_in[7];
    const float* a_dst2 = (const float*)d_in[8];
    const float* b2     = (const float*)d_in[9];
    const float* W3     = (const float*)d_in[10];
    const float* b3     = (const float*)d_in[11];
    const float* W4     = (const float*)d_in[12];
    const float* b4     = (const float*)d_in[13];
    float* out = (float*)d_out;

    const int N = NNODES, E = NEDGES, ET = E + N;
    const int NB = (N + 255) / 256;

    float* ws = (float*)d_ws;
    size_t o = 0;
    float* out2 = ws + o; o += (size_t)N * 64;
    float* as1  = ws + o; o += (size_t)N * 4;
    float* ad1  = ws + o; o += (size_t)N * 4;
    unsigned short* h1b   = (unsigned short*)(ws + o); o += (size_t)N * 128;  // N*256 bf16
    unsigned short* h2b   = (unsigned short*)(ws + o); o += (size_t)N * 32;   // N*64 bf16
    unsigned short* out1b = (unsigned short*)(ws + o); o += (size_t)N * 128;  // N*256 bf16
    unsigned short* xb    = (unsigned short*)(ws + o); o += (size_t)N * 64;   // N*128 bf16
    unsigned short* W1p   = (unsigned short*)(ws + o); o += 16384;  // 32768 ushort
    unsigned short* W2p   = (unsigned short*)(ws + o); o += 8192;   // 16384 ushort
    int* rowptr    = (int*)(ws + o);
    int* cursor    = rowptr + (N + 1);
    int* blocksums = cursor + N;
    int* csr_src   = blocksums + 256;

    dim3 blk(256);

    // ---- prep: cvt x, pack W1/W2, zero cursor (one dispatch) ----
    const int NCVT4 = N * 128 / 4;
    prep_kernel<<<(NCVT4 + 255) / 256, blk, 0, stream>>>(x, xb, W1, W1p, W2, W2p, cursor,
                                                         NCVT4, N);

    // ---- CSR build ----
    deg_hist<<<(ET + 255) / 256, blk, 0, stream>>>(ei, cursor, E, ET);
    scan_block<<<NB, blk, 0, stream>>>(cursor, rowptr, blocksums, N);
    scan_sums<<<1, blk, 0, stream>>>(blocksums, NB);
    scan_add<<<NB, blk, 0, stream>>>(rowptr, blocksums, cursor, N, ET);
    csr_scatter<<<(ET + 255) / 256, blk, 0, stream>>>(ei, cursor, csr_src, E, ET);

    // ---- Layer 1 (H=4, C=64) ----
    gemm_asad<128, 4><<<(N + 63) / 64, blk, 0, stream>>>(xb, W1p, a_src1, a_dst1, h1b, as1,
                                                         ad1, N);
    node_agg4<<<(N + 3) / 4, blk, 0, stream>>>(rowptr, csr_src, as1, ad1, h1b, b1, out1b, N);

    // ---- Layer 2 (H=1, C=64) ----
    gemm_asad<256, 1><<<(N + 63) / 64, blk, 0, stream>>>(out1b, W2p, a_src2, a_dst2, h2b, as1,
                                                         ad1, N);
    node_agg1<<<(N + 3) / 4, blk, 0, stream>>>(rowptr, csr_src, as1, ad1, h2b, b2, out2, N);

    // ---- Classifier ----
    classifier_kernel<<<(N + 63) / 64, blk, 0, stream>>>(out2, W3, b3, W4, b4, out, N);
}